// Round 1
// baseline (3274.541 us; speedup 1.0000x reference)
//
#include <hip/hip_runtime.h>
#include <hip/hip_fp16.h>
#include <math.h>

#define L_SEQ 1024
#define N_EMB 1024
#define N_HD 512
#define N_ITERS 20
#define EPITCH 1032   // 64 rows x 1032 halfs (pad 8) -> row stride 2064B, 16B aligned
#define SMEM_FUSED (64 * EPITCH * 2 + 4096 + 4096 + 256)

typedef short short8 __attribute__((ext_vector_type(8)));   // 8 bf16 = 4 VGPRs
typedef float floatx4 __attribute__((ext_vector_type(4)));  // MFMA acc

__device__ __forceinline__ unsigned short f2bf(float f) {
    unsigned int u = __float_as_uint(f);
    u += 0x7FFFu + ((u >> 16) & 1u);   // round-to-nearest-even
    return (unsigned short)(u >> 16);
}

// ---------------- prep: fp32 -> bf16 ----------------
__global__ __launch_bounds__(256) void convert_x(const float* __restrict__ x,
                                                 unsigned short* __restrict__ xb) {
    const int i = (blockIdx.x * 256 + threadIdx.x) << 4;  // 16 elems/thread
    unsigned short tmp[16];
#pragma unroll
    for (int p = 0; p < 4; ++p) {
        float4 f = *(const float4*)&x[i + (p << 2)];
        tmp[p * 4 + 0] = f2bf(f.x); tmp[p * 4 + 1] = f2bf(f.y);
        tmp[p * 4 + 2] = f2bf(f.z); tmp[p * 4 + 3] = f2bf(f.w);
    }
    *(uint4*)&xb[i]     = *(const uint4*)&tmp[0];
    *(uint4*)&xb[i + 8] = *(const uint4*)&tmp[8];
}

// Transpose all 4 weights to [n][k] bf16. z: 0..2 = Wq/Wk/Wv (1024x512), 3 = Wo (512x1024)
__global__ __launch_bounds__(256) void transpose_all(
    const float* __restrict__ Wq, const float* __restrict__ Wk,
    const float* __restrict__ Wv, const float* __restrict__ Wo,
    unsigned short* __restrict__ wqT, unsigned short* __restrict__ wkT,
    unsigned short* __restrict__ wvT, unsigned short* __restrict__ woT)
{
    const int z = blockIdx.z;
    const float* S; unsigned short* D; int rows, cols;
    if (z == 0)      { S = Wq; D = wqT; rows = 1024; cols = 512; }
    else if (z == 1) { S = Wk; D = wkT; rows = 1024; cols = 512; }
    else if (z == 2) { S = Wv; D = wvT; rows = 1024; cols = 512; }
    else             { S = Wo; D = woT; rows = 512;  cols = 1024; }
    const int n0 = blockIdx.x << 5, k0 = blockIdx.y << 5;
    if (n0 >= cols || k0 >= rows) return;
    __shared__ float Tls[32][33];
    const int t = threadIdx.x;
    const int rl = t >> 5, cl = t & 31;
#pragma unroll
    for (int i = 0; i < 4; ++i)
        Tls[rl + (i << 3)][cl] = S[(size_t)(k0 + rl + (i << 3)) * cols + n0 + cl];
    __syncthreads();
#pragma unroll
    for (int i = 0; i < 4; ++i)
        D[(size_t)(n0 + rl + (i << 3)) * rows + k0 + cl] = f2bf(Tls[cl][rl + (i << 3)]);
}

// ---------------- zero the barrier counters ----------------
__global__ void zero_cnt(int* __restrict__ cnt) {
    if ((int)threadIdx.x < N_ITERS * 16) cnt[threadIdx.x] = 0;
}

// ---------------- bf16 MFMA QKV projection ----------------
// q,k bf16 [bh][l][d]; v bf16 TRANSPOSED [bh][d][l]
__global__ __launch_bounds__(256) void mfma_qkv(
    const unsigned short* __restrict__ xb,
    const unsigned short* __restrict__ wqT, const unsigned short* __restrict__ wkT,
    const unsigned short* __restrict__ wvT,
    const float* __restrict__ bq, const float* __restrict__ bk, const float* __restrict__ bv,
    unsigned short* __restrict__ qb, unsigned short* __restrict__ kb,
    unsigned short* __restrict__ vt)
{
    const int pz = blockIdx.z;
    const unsigned short* wT = (pz == 0) ? wqT : (pz == 1) ? wkT : wvT;
    const float* bias = (pz == 0) ? bq : (pz == 1) ? bk : bv;
    __shared__ __align__(16) unsigned short Als[128 * 40];
    __shared__ __align__(16) unsigned short Bls[128 * 40];
    const int t = threadIdx.x;
    const int m0 = blockIdx.y << 7, n0 = blockIdx.x << 7;
    const int w = t >> 6, lane = t & 63;
    const int quad = lane >> 4, l16 = lane & 15;
    const int wr = w >> 1, wc = w & 1;
    const int ra = t >> 2, ka = (t & 3) << 3;
    floatx4 acc[4][4] = {};
    for (int k0 = 0; k0 < N_EMB; k0 += 32) {
        uint4 a0 = *(const uint4*)&xb[(size_t)(m0 + ra) * N_EMB + k0 + ka];
        uint4 a1 = *(const uint4*)&xb[(size_t)(m0 + ra + 64) * N_EMB + k0 + ka];
        uint4 b0 = *(const uint4*)&wT[(size_t)(n0 + ra) * N_EMB + k0 + ka];
        uint4 b1 = *(const uint4*)&wT[(size_t)(n0 + ra + 64) * N_EMB + k0 + ka];
        __syncthreads();
        *(uint4*)&Als[ra * 40 + ka] = a0;
        *(uint4*)&Als[(ra + 64) * 40 + ka] = a1;
        *(uint4*)&Bls[ra * 40 + ka] = b0;
        *(uint4*)&Bls[(ra + 64) * 40 + ka] = b1;
        __syncthreads();
        short8 af[4], bf[4];
#pragma unroll
        for (int i = 0; i < 4; ++i)
            af[i] = *(const short8*)&Als[(wr * 64 + i * 16 + l16) * 40 + quad * 8];
#pragma unroll
        for (int j = 0; j < 4; ++j)
            bf[j] = *(const short8*)&Bls[(wc * 64 + j * 16 + l16) * 40 + quad * 8];
#pragma unroll
        for (int i = 0; i < 4; ++i)
#pragma unroll
            for (int j = 0; j < 4; ++j)
                acc[i][j] = __builtin_amdgcn_mfma_f32_16x16x32_bf16(af[i], bf[j], acc[i][j], 0, 0, 0);
    }
    float bje[4];
    int hh[4], dd[4];
#pragma unroll
    for (int j = 0; j < 4; ++j) {
        int gn = n0 + wc * 64 + j * 16 + l16;
        bje[j] = bias[gn];
        hh[j] = gn >> 6; dd[j] = gn & 63;
    }
    unsigned short* qk = (pz == 0) ? qb : kb;
#pragma unroll
    for (int i = 0; i < 4; ++i)
#pragma unroll
    for (int p = 0; p < 4; ++p) {
        int gm = m0 + wr * 64 + i * 16 + quad * 4 + p;
        int bb = gm >> 10, l = gm & 1023;
#pragma unroll
        for (int j = 0; j < 4; ++j) {
            float val = acc[i][j][p] + bje[j];
            int bh = (bb << 3) + hh[j];
            if (pz < 2) qk[((size_t)bh * L_SEQ + l) * 64 + dd[j]] = f2bf(val);
            else        vt[((size_t)bh << 16) + ((size_t)dd[j] << 10) + l] = f2bf(val);
        }
    }
}

// ---------------- persistent fused: logits + 20 sinkhorn iters + P@V ----------------
// 256 blocks (bh = bid&15, chunk = bid>>4), 1024 threads, 1 block/CU.
// E tile (64 rows x 1024 cols, fp16, pitch 1032) lives entirely in LDS.
__global__ __launch_bounds__(1024, 4) void fused_sinkhorn(
    const unsigned short* __restrict__ qb, const unsigned short* __restrict__ kb,
    const unsigned short* __restrict__ vt, float* __restrict__ part_g,
    int* __restrict__ cnt, unsigned short* __restrict__ o_p)
{
    extern __shared__ char smem[];
    __half* Eld = (__half*)smem;                                   // 132096 B
    float* vls  = (float*)(smem + 64 * EPITCH * 2);                // 4096 B
    float* pls  = (float*)(smem + 64 * EPITCH * 2 + 4096);         // 4096 B
    float* uls  = (float*)(smem + 64 * EPITCH * 2 + 8192);         // 256 B

    const int bid = blockIdx.x;
    const int bh = bid & 15;          // same-bh siblings land on one XCD (perf only)
    const int chunk = bid >> 4;
    const int m0 = chunk << 6;
    const int t = threadIdx.x;
    const int w = t >> 6, lane = t & 63;
    const int quad = lane >> 4, l16 = lane & 15;

    // ---- phase 0: E = exp(Q K^T / 8) -> LDS fp16 ----
    {
        const int wr = w & 3, ns = w >> 2;   // 4 row-subtiles x 4 col-strips of 256
        const size_t qrow = ((size_t)(bh << 10) + m0 + (wr << 4) + l16) * 64;
        short8 af0 = *(const short8*)&qb[qrow + quad * 8];
        short8 af1 = *(const short8*)&qb[qrow + 32 + quad * 8];
        const int erow0 = (wr << 4) + (quad << 2);
        for (int tt = 0; tt < 16; ++tt) {
            const int n0 = (ns << 8) + (tt << 4);
            const size_t krow = ((size_t)(bh << 10) + n0 + l16) * 64;
            short8 bf0 = *(const short8*)&kb[krow + quad * 8];
            short8 bf1 = *(const short8*)&kb[krow + 32 + quad * 8];
            floatx4 acc = {};
            acc = __builtin_amdgcn_mfma_f32_16x16x32_bf16(af0, bf0, acc, 0, 0, 0);
            acc = __builtin_amdgcn_mfma_f32_16x16x32_bf16(af1, bf1, acc, 0, 0, 0);
#pragma unroll
            for (int p = 0; p < 4; ++p)
                Eld[(erow0 + p) * EPITCH + n0 + l16] = __float2half(__expf(acc[p] * 0.125f));
        }
    }
    vls[t] = 1.0f;
    __syncthreads();

    // ---- 20 sinkhorn iterations, E stays in LDS ----
    for (int it = 0; it < N_ITERS; ++it) {
        float vv[16];
#pragma unroll
        for (int p = 0; p < 2; ++p) {
            float4 a = *(const float4*)&vls[(p << 9) + (lane << 3)];
            float4 c = *(const float4*)&vls[(p << 9) + (lane << 3) + 4];
            vv[p * 8 + 0] = a.x; vv[p * 8 + 1] = a.y; vv[p * 8 + 2] = a.z; vv[p * 8 + 3] = a.w;
            vv[p * 8 + 4] = c.x; vv[p * 8 + 5] = c.y; vv[p * 8 + 6] = c.z; vv[p * 8 + 7] = c.w;
        }
        pls[t] = 0.0f;
        __syncthreads();

        float colacc[16] = {};
#pragma unroll
        for (int rr = 0; rr < 4; ++rr) {
            const int row = (w << 2) + rr;
            float e[16], s = 0.0f;
#pragma unroll
            for (int p = 0; p < 2; ++p) {
                uint4 hx = *(const uint4*)&Eld[row * EPITCH + (p << 9) + (lane << 3)];
                const __half* hp = (const __half*)&hx;
#pragma unroll
                for (int jj = 0; jj < 8; ++jj) {
                    float ev = __half2float(hp[jj]);
                    e[p * 8 + jj] = ev;
                    s += ev * vv[p * 8 + jj];
                }
            }
#pragma unroll
            for (int off = 32; off > 0; off >>= 1) s += __shfl_xor(s, off);
            const float ui = 1.0f / s;
            if (lane == 0) uls[row] = ui;
#pragma unroll
            for (int jj = 0; jj < 16; ++jj) colacc[jj] += e[jj] * ui;
        }
#pragma unroll
        for (int p = 0; p < 2; ++p)
#pragma unroll
            for (int jj = 0; jj < 8; ++jj)
                atomicAdd(&pls[(p << 9) + (lane << 3) + jj], colacc[p * 8 + jj]);
        __syncthreads();

        // publish this block's column partials (4 KB), then 16-block per-bh barrier
        float* pg = part_g + (((((it & 1) << 4) + bh) << 14) + (chunk << 10));
        pg[t] = pls[t];
        __threadfence();
        __syncthreads();
        if (t == 0) {
            atomicAdd(&cnt[(it << 4) + bh], 1);
            while (__hip_atomic_load(&cnt[(it << 4) + bh], __ATOMIC_ACQUIRE,
                                     __HIP_MEMORY_SCOPE_AGENT) < 16)
                __builtin_amdgcn_s_sleep(4);
        }
        __syncthreads();
        __threadfence();

        // merge: v_j = 1 / sum over the 16 chunks
        const float* pgb = part_g + ((((it & 1) << 4) + bh) << 14);
        float sv = 0.0f;
#pragma unroll
        for (int c = 0; c < 16; ++c) sv += pgb[(c << 10) + t];
        vls[t] = 1.0f / sv;
        __syncthreads();
    }

    // ---- P = u * E * v -> bf16 in place (conflict-free, same mapping as sweep) ----
    {
        float vvf[16];
#pragma unroll
        for (int p = 0; p < 2; ++p) {
            float4 a = *(const float4*)&vls[(p << 9) + (lane << 3)];
            float4 c = *(const float4*)&vls[(p << 9) + (lane << 3) + 4];
            vvf[p * 8 + 0] = a.x; vvf[p * 8 + 1] = a.y; vvf[p * 8 + 2] = a.z; vvf[p * 8 + 3] = a.w;
            vvf[p * 8 + 4] = c.x; vvf[p * 8 + 5] = c.y; vvf[p * 8 + 6] = c.z; vvf[p * 8 + 7] = c.w;
        }
#pragma unroll
        for (int rr = 0; rr < 4; ++rr) {
            const int row = (w << 2) + rr;
            const float ur = uls[row];
#pragma unroll
            for (int p = 0; p < 2; ++p) {
                uint4 hx = *(const uint4*)&Eld[row * EPITCH + (p << 9) + (lane << 3)];
                const __half* hp = (const __half*)&hx;
                unsigned short pk[8];
#pragma unroll
                for (int jj = 0; jj < 8; ++jj)
                    pk[jj] = f2bf(__half2float(hp[jj]) * ur * vvf[p * 8 + jj]);
                *(uint4*)&Eld[row * EPITCH + (p << 9) + (lane << 3)] = *(const uint4*)pk;
            }
        }
    }
    __syncthreads();

    // ---- O(64x64) = P(64x1024) @ V : A from LDS (padded pitch -> even banks), B from vt ----
    {
        const int wr = w >> 2, wc = w & 3;
        const size_t vtb = ((size_t)bh << 16) + ((size_t)((wc << 4) + l16) << 10);
        const int prow = ((wr << 4) + l16) * EPITCH;
        floatx4 oa0 = {}, oa1 = {};
#pragma unroll 4
        for (int ks = 0; ks < 16; ++ks) {
            short8 pa = *(const short8*)&Eld[prow + (ks << 5) + (quad << 3)];
            short8 vb = *(const short8*)&vt[vtb + (ks << 5) + (quad << 3)];
            oa0 = __builtin_amdgcn_mfma_f32_16x16x32_bf16(pa, vb, oa0, 0, 0, 0);
        }
#pragma unroll 4
        for (int ks = 16; ks < 32; ++ks) {
            short8 pa = *(const short8*)&Eld[prow + (ks << 5) + (quad << 3)];
            short8 vb = *(const short8*)&vt[vtb + (ks << 5) + (quad << 3)];
            oa1 = __builtin_amdgcn_mfma_f32_16x16x32_bf16(pa, vb, oa1, 0, 0, 0);
        }
        const int b = bh >> 3, h = bh & 7;
        const int dcol = (wc << 4) + l16;
#pragma unroll
        for (int p = 0; p < 4; ++p) {
            int l = m0 + (wr << 4) + (quad << 2) + p;
            o_p[((size_t)((b << 10) + l) << 9) + (h << 6) + dcol] = f2bf(oa0[p] + oa1[p]);
        }
    }
}

// ---------------- out = out_pre(bf16) @ Wo + bo via MFMA ----------------
__global__ __launch_bounds__(256) void mfma_out(
    const unsigned short* __restrict__ A,   // 2048 x 512 bf16
    const unsigned short* __restrict__ BT,  // woT: 1024 x 512 bf16
    const float* __restrict__ bo, float* __restrict__ C)
{
    __shared__ __align__(16) unsigned short Als[128 * 40];
    __shared__ __align__(16) unsigned short Bls[128 * 40];
    const int t = threadIdx.x;
    const int m0 = blockIdx.y << 7, n0 = blockIdx.x << 7;
    const int w = t >> 6, lane = t & 63;
    const int quad = lane >> 4, l16 = lane & 15;
    const int wr = w >> 1, wc = w & 1;
    const int ra = t >> 2, ka = (t & 3) << 3;
    floatx4 acc[4][4] = {};
    for (int k0 = 0; k0 < N_HD; k0 += 32) {
        uint4 a0 = *(const uint4*)&A[(size_t)(m0 + ra) * N_HD + k0 + ka];
        uint4 a1 = *(const uint4*)&A[(size_t)(m0 + ra + 64) * N_HD + k0 + ka];
        uint4 b0 = *(const uint4*)&BT[(size_t)(n0 + ra) * N_HD + k0 + ka];
        uint4 b1 = *(const uint4*)&BT[(size_t)(n0 + ra + 64) * N_HD + k0 + ka];
        __syncthreads();
        *(uint4*)&Als[ra * 40 + ka] = a0;
        *(uint4*)&Als[(ra + 64) * 40 + ka] = a1;
        *(uint4*)&Bls[ra * 40 + ka] = b0;
        *(uint4*)&Bls[(ra + 64) * 40 + ka] = b1;
        __syncthreads();
        short8 af[4], bf[4];
#pragma unroll
        for (int i = 0; i < 4; ++i)
            af[i] = *(const short8*)&Als[(wr * 64 + i * 16 + l16) * 40 + quad * 8];
#pragma unroll
        for (int j = 0; j < 4; ++j)
            bf[j] = *(const short8*)&Bls[(wc * 64 + j * 16 + l16) * 40 + quad * 8];
#pragma unroll
        for (int i = 0; i < 4; ++i)
#pragma unroll
            for (int j = 0; j < 4; ++j)
                acc[i][j] = __builtin_amdgcn_mfma_f32_16x16x32_bf16(af[i], bf[j], acc[i][j], 0, 0, 0);
    }
    float bje[4];
    int nn[4];
#pragma unroll
    for (int j = 0; j < 4; ++j) {
        nn[j] = n0 + wc * 64 + j * 16 + l16;
        bje[j] = bo[nn[j]];
    }
#pragma unroll
    for (int i = 0; i < 4; ++i)
#pragma unroll
    for (int p = 0; p < 4; ++p) {
        int m = m0 + wr * 64 + i * 16 + quad * 4 + p;
#pragma unroll
        for (int j = 0; j < 4; ++j)
            C[(size_t)m * N_EMB + nn[j]] = acc[i][j][p] + bje[j];
    }
}

extern "C" void kernel_launch(void* const* d_in, const int* in_sizes, int n_in,
                              void* d_out, int out_size, void* d_ws, size_t ws_size,
                              hipStream_t stream)
{
    const float* x  = (const float*)d_in[0];
    const float* Wq = (const float*)d_in[1];
    const float* bq = (const float*)d_in[2];
    const float* Wk = (const float*)d_in[3];
    const float* bk = (const float*)d_in[4];
    const float* Wv = (const float*)d_in[5];
    const float* bv = (const float*)d_in[6];
    const float* Wo = (const float*)d_in[7];
    const float* bo = (const float*)d_in[8];
    float* out = (float*)d_out;

    char* W = (char*)d_ws;
    unsigned short* xb  = (unsigned short*)(W);                    // 4 MB
    unsigned short* wqT = (unsigned short*)(W + (4ll  << 20));     // 1 MB
    unsigned short* wkT = (unsigned short*)(W + (5ll  << 20));     // 1 MB
    unsigned short* wvT = (unsigned short*)(W + (6ll  << 20));     // 1 MB
    unsigned short* woT = (unsigned short*)(W + (7ll  << 20));     // 1 MB
    unsigned short* qb  = (unsigned short*)(W + (8ll  << 20));     // 2 MB
    unsigned short* kb  = (unsigned short*)(W + (10ll << 20));     // 2 MB
    unsigned short* vt  = (unsigned short*)(W + (12ll << 20));     // 2 MB
    unsigned short* o_p = (unsigned short*)(W + (14ll << 20));     // 2 MB
    float* part_g       = (float*)(W + (16ll << 20));              // 2 MB (2 slots)
    int* cnt            = (int*)(W + (18ll << 20));                // 1.25 KB

    convert_x<<<512, 256, 0, stream>>>(x, xb);
    transpose_all<<<dim3(32, 32, 4), 256, 0, stream>>>(Wq, Wk, Wv, Wo, wqT, wkT, wvT, woT);
    zero_cnt<<<1, 320, 0, stream>>>(cnt);
    mfma_qkv<<<dim3(4, 16, 3), 256, 0, stream>>>(xb, wqT, wkT, wvT, bq, bk, bv, qb, kb, vt);

    void* fargs[] = { (void*)&qb, (void*)&kb, (void*)&vt,
                      (void*)&part_g, (void*)&cnt, (void*)&o_p };
    hipLaunchCooperativeKernel((const void*)fused_sinkhorn, dim3(256), dim3(1024),
                               fargs, SMEM_FUSED, stream);

    mfma_out<<<dim3(8, 16), 256, 0, stream>>>(o_p, woT, bo, out);
}

// Round 2
// 783.887 us; speedup vs baseline: 4.1773x; 4.1773x over previous
//
#include <hip/hip_runtime.h>
#include <hip/hip_fp16.h>
#include <math.h>

#define L_SEQ 1024
#define N_EMB 1024
#define N_HD 512
#define N_ITERS 20
#define EPITCH 1032   // 64 rows x 1032 halfs (pad 8) -> row stride 2064B, 16B aligned
#define SMEM_FUSED (64 * EPITCH * 2 + 4096 + 4096 + 256)
#define PART_FLOATS (N_ITERS * 16 * 1024)   // per-iteration slots, pre-zeroed

typedef short short8 __attribute__((ext_vector_type(8)));   // 8 bf16 = 4 VGPRs
typedef float floatx4 __attribute__((ext_vector_type(4)));  // MFMA acc

__device__ __forceinline__ unsigned short f2bf(float f) {
    unsigned int u = __float_as_uint(f);
    u += 0x7FFFu + ((u >> 16) & 1u);   // round-to-nearest-even
    return (unsigned short)(u >> 16);
}

// ---------------- prep: fp32 -> bf16 ----------------
__global__ __launch_bounds__(256) void convert_x(const float* __restrict__ x,
                                                 unsigned short* __restrict__ xb) {
    const int i = (blockIdx.x * 256 + threadIdx.x) << 4;  // 16 elems/thread
    unsigned short tmp[16];
#pragma unroll
    for (int p = 0; p < 4; ++p) {
        float4 f = *(const float4*)&x[i + (p << 2)];
        tmp[p * 4 + 0] = f2bf(f.x); tmp[p * 4 + 1] = f2bf(f.y);
        tmp[p * 4 + 2] = f2bf(f.z); tmp[p * 4 + 3] = f2bf(f.w);
    }
    *(uint4*)&xb[i]     = *(const uint4*)&tmp[0];
    *(uint4*)&xb[i + 8] = *(const uint4*)&tmp[8];
}

// Transpose all 4 weights to [n][k] bf16. z: 0..2 = Wq/Wk/Wv (1024x512), 3 = Wo (512x1024)
__global__ __launch_bounds__(256) void transpose_all(
    const float* __restrict__ Wq, const float* __restrict__ Wk,
    const float* __restrict__ Wv, const float* __restrict__ Wo,
    unsigned short* __restrict__ wqT, unsigned short* __restrict__ wkT,
    unsigned short* __restrict__ wvT, unsigned short* __restrict__ woT)
{
    const int z = blockIdx.z;
    const float* S; unsigned short* D; int rows, cols;
    if (z == 0)      { S = Wq; D = wqT; rows = 1024; cols = 512; }
    else if (z == 1) { S = Wk; D = wkT; rows = 1024; cols = 512; }
    else if (z == 2) { S = Wv; D = wvT; rows = 1024; cols = 512; }
    else             { S = Wo; D = woT; rows = 512;  cols = 1024; }
    const int n0 = blockIdx.x << 5, k0 = blockIdx.y << 5;
    if (n0 >= cols || k0 >= rows) return;
    __shared__ float Tls[32][33];
    const int t = threadIdx.x;
    const int rl = t >> 5, cl = t & 31;
#pragma unroll
    for (int i = 0; i < 4; ++i)
        Tls[rl + (i << 3)][cl] = S[(size_t)(k0 + rl + (i << 3)) * cols + n0 + cl];
    __syncthreads();
#pragma unroll
    for (int i = 0; i < 4; ++i)
        D[(size_t)(n0 + rl + (i << 3)) * rows + k0 + cl] = f2bf(Tls[cl][rl + (i << 3)]);
}

// ---------------- zero the partial-sum slots + barrier counters ----------------
__global__ __launch_bounds__(256) void zero_ws(float* __restrict__ part, int* __restrict__ cnt) {
    const int idx = blockIdx.x * 256 + threadIdx.x;
    if (idx < PART_FLOATS) part[idx] = 0.0f;
    const int r = idx - PART_FLOATS;
    if (r >= 0 && r < N_ITERS * 16) cnt[r] = 0;
}

// ---------------- bf16 MFMA QKV projection ----------------
// q,k bf16 [bh][l][d]; v bf16 TRANSPOSED [bh][d][l]
__global__ __launch_bounds__(256) void mfma_qkv(
    const unsigned short* __restrict__ xb,
    const unsigned short* __restrict__ wqT, const unsigned short* __restrict__ wkT,
    const unsigned short* __restrict__ wvT,
    const float* __restrict__ bq, const float* __restrict__ bk, const float* __restrict__ bv,
    unsigned short* __restrict__ qb, unsigned short* __restrict__ kb,
    unsigned short* __restrict__ vt)
{
    const int pz = blockIdx.z;
    const unsigned short* wT = (pz == 0) ? wqT : (pz == 1) ? wkT : wvT;
    const float* bias = (pz == 0) ? bq : (pz == 1) ? bk : bv;
    __shared__ __align__(16) unsigned short Als[128 * 40];
    __shared__ __align__(16) unsigned short Bls[128 * 40];
    const int t = threadIdx.x;
    const int m0 = blockIdx.y << 7, n0 = blockIdx.x << 7;
    const int w = t >> 6, lane = t & 63;
    const int quad = lane >> 4, l16 = lane & 15;
    const int wr = w >> 1, wc = w & 1;
    const int ra = t >> 2, ka = (t & 3) << 3;
    floatx4 acc[4][4] = {};
    for (int k0 = 0; k0 < N_EMB; k0 += 32) {
        uint4 a0 = *(const uint4*)&xb[(size_t)(m0 + ra) * N_EMB + k0 + ka];
        uint4 a1 = *(const uint4*)&xb[(size_t)(m0 + ra + 64) * N_EMB + k0 + ka];
        uint4 b0 = *(const uint4*)&wT[(size_t)(n0 + ra) * N_EMB + k0 + ka];
        uint4 b1 = *(const uint4*)&wT[(size_t)(n0 + ra + 64) * N_EMB + k0 + ka];
        __syncthreads();
        *(uint4*)&Als[ra * 40 + ka] = a0;
        *(uint4*)&Als[(ra + 64) * 40 + ka] = a1;
        *(uint4*)&Bls[ra * 40 + ka] = b0;
        *(uint4*)&Bls[(ra + 64) * 40 + ka] = b1;
        __syncthreads();
        short8 af[4], bf[4];
#pragma unroll
        for (int i = 0; i < 4; ++i)
            af[i] = *(const short8*)&Als[(wr * 64 + i * 16 + l16) * 40 + quad * 8];
#pragma unroll
        for (int j = 0; j < 4; ++j)
            bf[j] = *(const short8*)&Bls[(wc * 64 + j * 16 + l16) * 40 + quad * 8];
#pragma unroll
        for (int i = 0; i < 4; ++i)
#pragma unroll
            for (int j = 0; j < 4; ++j)
                acc[i][j] = __builtin_amdgcn_mfma_f32_16x16x32_bf16(af[i], bf[j], acc[i][j], 0, 0, 0);
    }
    float bje[4];
    int hh[4], dd[4];
#pragma unroll
    for (int j = 0; j < 4; ++j) {
        int gn = n0 + wc * 64 + j * 16 + l16;
        bje[j] = bias[gn];
        hh[j] = gn >> 6; dd[j] = gn & 63;
    }
    unsigned short* qk = (pz == 0) ? qb : kb;
#pragma unroll
    for (int i = 0; i < 4; ++i)
#pragma unroll
    for (int p = 0; p < 4; ++p) {
        int gm = m0 + wr * 64 + i * 16 + quad * 4 + p;
        int bb = gm >> 10, l = gm & 1023;
#pragma unroll
        for (int j = 0; j < 4; ++j) {
            float val = acc[i][j][p] + bje[j];
            int bh = (bb << 3) + hh[j];
            if (pz < 2) qk[((size_t)bh * L_SEQ + l) * 64 + dd[j]] = f2bf(val);
            else        vt[((size_t)bh << 16) + ((size_t)dd[j] << 10) + l] = f2bf(val);
        }
    }
}

// ---------------- persistent fused: logits + 20 sinkhorn iters + P@V ----------------
// 256 blocks (bh = bid&15, chunk = bid>>4), 1024 threads, 1 block/CU.
// E tile (64 rows x 1024 cols, fp16, pitch 1032) lives entirely in LDS.
// Cross-block exchange is ATOMICS-ONLY (no __threadfence -> no per-wave L2 wb/inv storm).
__global__ __launch_bounds__(1024, 4) void fused_sinkhorn(
    const unsigned short* __restrict__ qb, const unsigned short* __restrict__ kb,
    const unsigned short* __restrict__ vt, float* __restrict__ part_g,
    int* __restrict__ cnt, unsigned short* __restrict__ o_p)
{
    extern __shared__ char smem[];
    __half* Eld = (__half*)smem;                                   // 132096 B
    float* vls  = (float*)(smem + 64 * EPITCH * 2);                // 4096 B
    float* pls  = (float*)(smem + 64 * EPITCH * 2 + 4096);         // 4096 B
    float* uls  = (float*)(smem + 64 * EPITCH * 2 + 8192);         // 256 B

    const int bid = blockIdx.x;
    const int bh = bid & 15;          // same-bh siblings land on one XCD (perf only)
    const int chunk = bid >> 4;
    const int m0 = chunk << 6;
    const int t = threadIdx.x;
    const int w = t >> 6, lane = t & 63;
    const int quad = lane >> 4, l16 = lane & 15;

    // ---- phase 0: E = exp(Q K^T / 8) -> LDS fp16 ----
    {
        const int wr = w & 3, ns = w >> 2;   // 4 row-subtiles x 4 col-strips of 256
        const size_t qrow = ((size_t)(bh << 10) + m0 + (wr << 4) + l16) * 64;
        short8 af0 = *(const short8*)&qb[qrow + quad * 8];
        short8 af1 = *(const short8*)&qb[qrow + 32 + quad * 8];
        const int erow0 = (wr << 4) + (quad << 2);
        for (int tt = 0; tt < 16; ++tt) {
            const int n0 = (ns << 8) + (tt << 4);
            const size_t krow = ((size_t)(bh << 10) + n0 + l16) * 64;
            short8 bf0 = *(const short8*)&kb[krow + quad * 8];
            short8 bf1 = *(const short8*)&kb[krow + 32 + quad * 8];
            floatx4 acc = {};
            acc = __builtin_amdgcn_mfma_f32_16x16x32_bf16(af0, bf0, acc, 0, 0, 0);
            acc = __builtin_amdgcn_mfma_f32_16x16x32_bf16(af1, bf1, acc, 0, 0, 0);
#pragma unroll
            for (int p = 0; p < 4; ++p)
                Eld[(erow0 + p) * EPITCH + n0 + l16] = __float2half(__expf(acc[p] * 0.125f));
        }
    }
    vls[t] = 1.0f;
    __syncthreads();

    // ---- 20 sinkhorn iterations, E stays in LDS ----
    for (int it = 0; it < N_ITERS; ++it) {
        float vv[16];
#pragma unroll
        for (int p = 0; p < 2; ++p) {
            float4 a = *(const float4*)&vls[(p << 9) + (lane << 3)];
            float4 c = *(const float4*)&vls[(p << 9) + (lane << 3) + 4];
            vv[p * 8 + 0] = a.x; vv[p * 8 + 1] = a.y; vv[p * 8 + 2] = a.z; vv[p * 8 + 3] = a.w;
            vv[p * 8 + 4] = c.x; vv[p * 8 + 5] = c.y; vv[p * 8 + 6] = c.z; vv[p * 8 + 7] = c.w;
        }
        pls[t] = 0.0f;
        __syncthreads();

        float colacc[16] = {};
#pragma unroll
        for (int rr = 0; rr < 4; ++rr) {
            const int row = (w << 2) + rr;
            float e[16], s = 0.0f;
#pragma unroll
            for (int p = 0; p < 2; ++p) {
                uint4 hx = *(const uint4*)&Eld[row * EPITCH + (p << 9) + (lane << 3)];
                const __half* hp = (const __half*)&hx;
#pragma unroll
                for (int jj = 0; jj < 8; ++jj) {
                    float ev = __half2float(hp[jj]);
                    e[p * 8 + jj] = ev;
                    s += ev * vv[p * 8 + jj];
                }
            }
#pragma unroll
            for (int off = 32; off > 0; off >>= 1) s += __shfl_xor(s, off);
            const float ui = 1.0f / s;
            if (lane == 0) uls[row] = ui;
#pragma unroll
            for (int jj = 0; jj < 16; ++jj) colacc[jj] += e[jj] * ui;
        }
#pragma unroll
        for (int p = 0; p < 2; ++p)
#pragma unroll
            for (int jj = 0; jj < 8; ++jj)
                atomicAdd(&pls[(p << 9) + (lane << 3) + jj], colacc[p * 8 + jj]);
        __syncthreads();

        // global accumulate: ONE device-scope atomicAdd per thread into this
        // iteration's pre-zeroed per-bh slot (atomics are LLC-coherent, no fence).
        float* pg = part_g + (((it << 4) + bh) << 10);
        atomicAdd(&pg[t], pls[t]);
        __syncthreads();   // drains vmcnt(0): all 16 waves' adds complete

        if (t == 0) {
            __hip_atomic_fetch_add(&cnt[(it << 4) + bh], 1, __ATOMIC_RELEASE,
                                   __HIP_MEMORY_SCOPE_AGENT);
            while (__hip_atomic_load(&cnt[(it << 4) + bh], __ATOMIC_ACQUIRE,
                                     __HIP_MEMORY_SCOPE_AGENT) < 16)
                __builtin_amdgcn_s_sleep(1);
        }
        __syncthreads();

        // v_j = 1/total; relaxed agent load bypasses stale L1/L2
        const float sv = __hip_atomic_load(&pg[t], __ATOMIC_RELAXED,
                                           __HIP_MEMORY_SCOPE_AGENT);
        vls[t] = 1.0f / sv;
        __syncthreads();
    }

    // ---- P = u * E * v -> bf16 in place (conflict-free, same mapping as sweep) ----
    {
        float vvf[16];
#pragma unroll
        for (int p = 0; p < 2; ++p) {
            float4 a = *(const float4*)&vls[(p << 9) + (lane << 3)];
            float4 c = *(const float4*)&vls[(p << 9) + (lane << 3) + 4];
            vvf[p * 8 + 0] = a.x; vvf[p * 8 + 1] = a.y; vvf[p * 8 + 2] = a.z; vvf[p * 8 + 3] = a.w;
            vvf[p * 8 + 4] = c.x; vvf[p * 8 + 5] = c.y; vvf[p * 8 + 6] = c.z; vvf[p * 8 + 7] = c.w;
        }
#pragma unroll
        for (int rr = 0; rr < 4; ++rr) {
            const int row = (w << 2) + rr;
            const float ur = uls[row];
#pragma unroll
            for (int p = 0; p < 2; ++p) {
                uint4 hx = *(const uint4*)&Eld[row * EPITCH + (p << 9) + (lane << 3)];
                const __half* hp = (const __half*)&hx;
                unsigned short pk[8];
#pragma unroll
                for (int jj = 0; jj < 8; ++jj)
                    pk[jj] = f2bf(__half2float(hp[jj]) * ur * vvf[p * 8 + jj]);
                *(uint4*)&Eld[row * EPITCH + (p << 9) + (lane << 3)] = *(const uint4*)pk;
            }
        }
    }
    __syncthreads();

    // ---- O(64x64) = P(64x1024) @ V : A from LDS (padded pitch -> even banks), B from vt ----
    {
        const int wr = w >> 2, wc = w & 3;
        const size_t vtb = ((size_t)bh << 16) + ((size_t)((wc << 4) + l16) << 10);
        const int prow = ((wr << 4) + l16) * EPITCH;
        floatx4 oa0 = {}, oa1 = {};
#pragma unroll 4
        for (int ks = 0; ks < 16; ++ks) {
            short8 pa = *(const short8*)&Eld[prow + (ks << 5) + (quad << 3)];
            short8 vb = *(const short8*)&vt[vtb + (ks << 5) + (quad << 3)];
            oa0 = __builtin_amdgcn_mfma_f32_16x16x32_bf16(pa, vb, oa0, 0, 0, 0);
        }
#pragma unroll 4
        for (int ks = 16; ks < 32; ++ks) {
            short8 pa = *(const short8*)&Eld[prow + (ks << 5) + (quad << 3)];
            short8 vb = *(const short8*)&vt[vtb + (ks << 5) + (quad << 3)];
            oa1 = __builtin_amdgcn_mfma_f32_16x16x32_bf16(pa, vb, oa1, 0, 0, 0);
        }
        const int b = bh >> 3, h = bh & 7;
        const int dcol = (wc << 4) + l16;
#pragma unroll
        for (int p = 0; p < 4; ++p) {
            int l = m0 + (wr << 4) + (quad << 2) + p;
            o_p[((size_t)((b << 10) + l) << 9) + (h << 6) + dcol] = f2bf(oa0[p] + oa1[p]);
        }
    }
}

// ---------------- out = out_pre(bf16) @ Wo + bo via MFMA ----------------
__global__ __launch_bounds__(256) void mfma_out(
    const unsigned short* __restrict__ A,   // 2048 x 512 bf16
    const unsigned short* __restrict__ BT,  // woT: 1024 x 512 bf16
    const float* __restrict__ bo, float* __restrict__ C)
{
    __shared__ __align__(16) unsigned short Als[128 * 40];
    __shared__ __align__(16) unsigned short Bls[128 * 40];
    const int t = threadIdx.x;
    const int m0 = blockIdx.y << 7, n0 = blockIdx.x << 7;
    const int w = t >> 6, lane = t & 63;
    const int quad = lane >> 4, l16 = lane & 15;
    const int wr = w >> 1, wc = w & 1;
    const int ra = t >> 2, ka = (t & 3) << 3;
    floatx4 acc[4][4] = {};
    for (int k0 = 0; k0 < N_HD; k0 += 32) {
        uint4 a0 = *(const uint4*)&A[(size_t)(m0 + ra) * N_HD + k0 + ka];
        uint4 a1 = *(const uint4*)&A[(size_t)(m0 + ra + 64) * N_HD + k0 + ka];
        uint4 b0 = *(const uint4*)&BT[(size_t)(n0 + ra) * N_HD + k0 + ka];
        uint4 b1 = *(const uint4*)&BT[(size_t)(n0 + ra + 64) * N_HD + k0 + ka];
        __syncthreads();
        *(uint4*)&Als[ra * 40 + ka] = a0;
        *(uint4*)&Als[(ra + 64) * 40 + ka] = a1;
        *(uint4*)&Bls[ra * 40 + ka] = b0;
        *(uint4*)&Bls[(ra + 64) * 40 + ka] = b1;
        __syncthreads();
        short8 af[4], bf[4];
#pragma unroll
        for (int i = 0; i < 4; ++i)
            af[i] = *(const short8*)&Als[(wr * 64 + i * 16 + l16) * 40 + quad * 8];
#pragma unroll
        for (int j = 0; j < 4; ++j)
            bf[j] = *(const short8*)&Bls[(wc * 64 + j * 16 + l16) * 40 + quad * 8];
#pragma unroll
        for (int i = 0; i < 4; ++i)
#pragma unroll
            for (int j = 0; j < 4; ++j)
                acc[i][j] = __builtin_amdgcn_mfma_f32_16x16x32_bf16(af[i], bf[j], acc[i][j], 0, 0, 0);
    }
    float bje[4];
    int nn[4];
#pragma unroll
    for (int j = 0; j < 4; ++j) {
        nn[j] = n0 + wc * 64 + j * 16 + l16;
        bje[j] = bo[nn[j]];
    }
#pragma unroll
    for (int i = 0; i < 4; ++i)
#pragma unroll
    for (int p = 0; p < 4; ++p) {
        int m = m0 + wr * 64 + i * 16 + quad * 4 + p;
#pragma unroll
        for (int j = 0; j < 4; ++j)
            C[(size_t)m * N_EMB + nn[j]] = acc[i][j][p] + bje[j];
    }
}

extern "C" void kernel_launch(void* const* d_in, const int* in_sizes, int n_in,
                              void* d_out, int out_size, void* d_ws, size_t ws_size,
                              hipStream_t stream)
{
    const float* x  = (const float*)d_in[0];
    const float* Wq = (const float*)d_in[1];
    const float* bq = (const float*)d_in[2];
    const float* Wk = (const float*)d_in[3];
    const float* bk = (const float*)d_in[4];
    const float* Wv = (const float*)d_in[5];
    const float* bv = (const float*)d_in[6];
    const float* Wo = (const float*)d_in[7];
    const float* bo = (const float*)d_in[8];
    float* out = (float*)d_out;

    char* W = (char*)d_ws;
    unsigned short* xb  = (unsigned short*)(W);                    // 4 MB
    unsigned short* wqT = (unsigned short*)(W + (4ll  << 20));     // 1 MB
    unsigned short* wkT = (unsigned short*)(W + (5ll  << 20));     // 1 MB
    unsigned short* wvT = (unsigned short*)(W + (6ll  << 20));     // 1 MB
    unsigned short* woT = (unsigned short*)(W + (7ll  << 20));     // 1 MB
    unsigned short* qb  = (unsigned short*)(W + (8ll  << 20));     // 2 MB
    unsigned short* kb  = (unsigned short*)(W + (10ll << 20));     // 2 MB
    unsigned short* vt  = (unsigned short*)(W + (12ll << 20));     // 2 MB
    unsigned short* o_p = (unsigned short*)(W + (14ll << 20));     // 2 MB
    float* part_g       = (float*)(W + (16ll << 20));              // 1.25 MB (20 slots)
    int* cnt            = (int*)(W + (18ll << 20));                // 1.25 KB

    convert_x<<<512, 256, 0, stream>>>(x, xb);
    transpose_all<<<dim3(32, 32, 4), 256, 0, stream>>>(Wq, Wk, Wv, Wo, wqT, wkT, wvT, woT);
    zero_ws<<<1282, 256, 0, stream>>>(part_g, cnt);
    mfma_qkv<<<dim3(4, 16, 3), 256, 0, stream>>>(xb, wqT, wkT, wvT, bq, bk, bv, qb, kb, vt);

    void* fargs[] = { (void*)&qb, (void*)&kb, (void*)&vt,
                      (void*)&part_g, (void*)&cnt, (void*)&o_p };
    hipLaunchCooperativeKernel((const void*)fused_sinkhorn, dim3(256), dim3(1024),
                               fargs, SMEM_FUSED, stream);

    mfma_out<<<dim3(8, 16), 256, 0, stream>>>(o_p, woT, bo, out);
}

// Round 3
// 773.599 us; speedup vs baseline: 4.2329x; 1.0133x over previous
//
#include <hip/hip_runtime.h>
#include <hip/hip_fp16.h>
#include <math.h>

#define L_SEQ 1024
#define N_EMB 1024
#define N_HD 512
#define N_ITERS 20
#define EPITCH 1032   // 64 rows x 1032 halfs (pad 8) -> row stride 2064B, 16B aligned
// pls gets +1-float-per-32 swizzle: 1024 -> 1056 entries
#define PADIDX(c) ((c) + ((c) >> 5))
#define SMEM_FUSED (64 * EPITCH * 2 + 4096 + 4224 + 256)
#define PART_FLOATS (N_ITERS * 16 * 1024)   // per-iteration slots, pre-zeroed

typedef short short8 __attribute__((ext_vector_type(8)));   // 8 bf16 = 4 VGPRs
typedef float floatx4 __attribute__((ext_vector_type(4)));  // MFMA acc

__device__ __forceinline__ unsigned short f2bf(float f) {
    unsigned int u = __float_as_uint(f);
    u += 0x7FFFu + ((u >> 16) & 1u);   // round-to-nearest-even
    return (unsigned short)(u >> 16);
}

// ---------------- prep: fp32 -> bf16 ----------------
__global__ __launch_bounds__(256) void convert_x(const float* __restrict__ x,
                                                 unsigned short* __restrict__ xb) {
    const int i = (blockIdx.x * 256 + threadIdx.x) << 4;  // 16 elems/thread
    unsigned short tmp[16];
#pragma unroll
    for (int p = 0; p < 4; ++p) {
        float4 f = *(const float4*)&x[i + (p << 2)];
        tmp[p * 4 + 0] = f2bf(f.x); tmp[p * 4 + 1] = f2bf(f.y);
        tmp[p * 4 + 2] = f2bf(f.z); tmp[p * 4 + 3] = f2bf(f.w);
    }
    *(uint4*)&xb[i]     = *(const uint4*)&tmp[0];
    *(uint4*)&xb[i + 8] = *(const uint4*)&tmp[8];
}

// Transpose all 4 weights to [n][k] bf16. z: 0..2 = Wq/Wk/Wv (1024x512), 3 = Wo (512x1024)
__global__ __launch_bounds__(256) void transpose_all(
    const float* __restrict__ Wq, const float* __restrict__ Wk,
    const float* __restrict__ Wv, const float* __restrict__ Wo,
    unsigned short* __restrict__ wqT, unsigned short* __restrict__ wkT,
    unsigned short* __restrict__ wvT, unsigned short* __restrict__ woT)
{
    const int z = blockIdx.z;
    const float* S; unsigned short* D; int rows, cols;
    if (z == 0)      { S = Wq; D = wqT; rows = 1024; cols = 512; }
    else if (z == 1) { S = Wk; D = wkT; rows = 1024; cols = 512; }
    else if (z == 2) { S = Wv; D = wvT; rows = 1024; cols = 512; }
    else             { S = Wo; D = woT; rows = 512;  cols = 1024; }
    const int n0 = blockIdx.x << 5, k0 = blockIdx.y << 5;
    if (n0 >= cols || k0 >= rows) return;
    __shared__ float Tls[32][33];
    const int t = threadIdx.x;
    const int rl = t >> 5, cl = t & 31;
#pragma unroll
    for (int i = 0; i < 4; ++i)
        Tls[rl + (i << 3)][cl] = S[(size_t)(k0 + rl + (i << 3)) * cols + n0 + cl];
    __syncthreads();
#pragma unroll
    for (int i = 0; i < 4; ++i)
        D[(size_t)(n0 + rl + (i << 3)) * rows + k0 + cl] = f2bf(Tls[cl][rl + (i << 3)]);
}

// ---------------- zero the partial-sum slots + barrier counters ----------------
__global__ __launch_bounds__(256) void zero_ws(float* __restrict__ part, int* __restrict__ cnt) {
    const int idx = blockIdx.x * 256 + threadIdx.x;
    if (idx < PART_FLOATS) part[idx] = 0.0f;
    const int r = idx - PART_FLOATS;
    if (r >= 0 && r < N_ITERS * 16) cnt[r] = 0;
}

// ---------------- bf16 MFMA QKV projection ----------------
// q,k bf16 [bh][l][d]; v bf16 TRANSPOSED [bh][d][l]
__global__ __launch_bounds__(256) void mfma_qkv(
    const unsigned short* __restrict__ xb,
    const unsigned short* __restrict__ wqT, const unsigned short* __restrict__ wkT,
    const unsigned short* __restrict__ wvT,
    const float* __restrict__ bq, const float* __restrict__ bk, const float* __restrict__ bv,
    unsigned short* __restrict__ qb, unsigned short* __restrict__ kb,
    unsigned short* __restrict__ vt)
{
    const int pz = blockIdx.z;
    const unsigned short* wT = (pz == 0) ? wqT : (pz == 1) ? wkT : wvT;
    const float* bias = (pz == 0) ? bq : (pz == 1) ? bk : bv;
    __shared__ __align__(16) unsigned short Als[128 * 40];
    __shared__ __align__(16) unsigned short Bls[128 * 40];
    const int t = threadIdx.x;
    const int m0 = blockIdx.y << 7, n0 = blockIdx.x << 7;
    const int w = t >> 6, lane = t & 63;
    const int quad = lane >> 4, l16 = lane & 15;
    const int wr = w >> 1, wc = w & 1;
    const int ra = t >> 2, ka = (t & 3) << 3;
    floatx4 acc[4][4] = {};
    for (int k0 = 0; k0 < N_EMB; k0 += 32) {
        uint4 a0 = *(const uint4*)&xb[(size_t)(m0 + ra) * N_EMB + k0 + ka];
        uint4 a1 = *(const uint4*)&xb[(size_t)(m0 + ra + 64) * N_EMB + k0 + ka];
        uint4 b0 = *(const uint4*)&wT[(size_t)(n0 + ra) * N_EMB + k0 + ka];
        uint4 b1 = *(const uint4*)&wT[(size_t)(n0 + ra + 64) * N_EMB + k0 + ka];
        __syncthreads();
        *(uint4*)&Als[ra * 40 + ka] = a0;
        *(uint4*)&Als[(ra + 64) * 40 + ka] = a1;
        *(uint4*)&Bls[ra * 40 + ka] = b0;
        *(uint4*)&Bls[(ra + 64) * 40 + ka] = b1;
        __syncthreads();
        short8 af[4], bf[4];
#pragma unroll
        for (int i = 0; i < 4; ++i)
            af[i] = *(const short8*)&Als[(wr * 64 + i * 16 + l16) * 40 + quad * 8];
#pragma unroll
        for (int j = 0; j < 4; ++j)
            bf[j] = *(const short8*)&Bls[(wc * 64 + j * 16 + l16) * 40 + quad * 8];
#pragma unroll
        for (int i = 0; i < 4; ++i)
#pragma unroll
            for (int j = 0; j < 4; ++j)
                acc[i][j] = __builtin_amdgcn_mfma_f32_16x16x32_bf16(af[i], bf[j], acc[i][j], 0, 0, 0);
    }
    float bje[4];
    int hh[4], dd[4];
#pragma unroll
    for (int j = 0; j < 4; ++j) {
        int gn = n0 + wc * 64 + j * 16 + l16;
        bje[j] = bias[gn];
        hh[j] = gn >> 6; dd[j] = gn & 63;
    }
    unsigned short* qk = (pz == 0) ? qb : kb;
#pragma unroll
    for (int i = 0; i < 4; ++i)
#pragma unroll
    for (int p = 0; p < 4; ++p) {
        int gm = m0 + wr * 64 + i * 16 + quad * 4 + p;
        int bb = gm >> 10, l = gm & 1023;
#pragma unroll
        for (int j = 0; j < 4; ++j) {
            float val = acc[i][j][p] + bje[j];
            int bh = (bb << 3) + hh[j];
            if (pz < 2) qk[((size_t)bh * L_SEQ + l) * 64 + dd[j]] = f2bf(val);
            else        vt[((size_t)bh << 16) + ((size_t)dd[j] << 10) + l] = f2bf(val);
        }
    }
}

// ---------------- persistent fused: logits + 20 sinkhorn iters + P@V ----------------
// 256 blocks (bh = bid&15, chunk = bid>>4), 1024 threads, 1 block/CU.
// E tile (64 rows x 1024 cols, fp16, pitch 1032) lives entirely in LDS.
// Cross-block: device atomics only; RELAXED spin + single acquire (no per-poll inv).
__global__ __launch_bounds__(1024, 4) void fused_sinkhorn(
    const unsigned short* __restrict__ qb, const unsigned short* __restrict__ kb,
    const unsigned short* __restrict__ vt, float* __restrict__ part_g,
    int* __restrict__ cnt, unsigned short* __restrict__ o_p)
{
    extern __shared__ char smem[];
    __half* Eld = (__half*)smem;                                   // 132096 B
    float* vls  = (float*)(smem + 64 * EPITCH * 2);                // 4096 B
    float* pls  = (float*)(smem + 64 * EPITCH * 2 + 4096);         // 4224 B (swizzled 1056)
    float* uls  = (float*)(smem + 64 * EPITCH * 2 + 4096 + 4224);  // 256 B

    const int bid = blockIdx.x;
    const int bh = bid & 15;          // same-bh siblings land on one XCD (perf only)
    const int chunk = bid >> 4;
    const int m0 = chunk << 6;
    const int t = threadIdx.x;
    const int w = t >> 6, lane = t & 63;
    const int quad = lane >> 4, l16 = lane & 15;

    // ---- phase 0: E = exp(Q K^T / 8) -> LDS fp16 ----
    {
        const int wr = w & 3, ns = w >> 2;   // 4 row-subtiles x 4 col-strips of 256
        const size_t qrow = ((size_t)(bh << 10) + m0 + (wr << 4) + l16) * 64;
        short8 af0 = *(const short8*)&qb[qrow + quad * 8];
        short8 af1 = *(const short8*)&qb[qrow + 32 + quad * 8];
        const int erow0 = (wr << 4) + (quad << 2);
        for (int tt = 0; tt < 16; ++tt) {
            const int n0 = (ns << 8) + (tt << 4);
            const size_t krow = ((size_t)(bh << 10) + n0 + l16) * 64;
            short8 bf0 = *(const short8*)&kb[krow + quad * 8];
            short8 bf1 = *(const short8*)&kb[krow + 32 + quad * 8];
            floatx4 acc = {};
            acc = __builtin_amdgcn_mfma_f32_16x16x32_bf16(af0, bf0, acc, 0, 0, 0);
            acc = __builtin_amdgcn_mfma_f32_16x16x32_bf16(af1, bf1, acc, 0, 0, 0);
#pragma unroll
            for (int p = 0; p < 4; ++p)
                Eld[(erow0 + p) * EPITCH + n0 + l16] = __float2half(__expf(acc[p] * 0.125f));
        }
    }
    vls[t] = 1.0f;
    __syncthreads();

    // ---- 20 sinkhorn iterations, E stays in LDS ----
    for (int it = 0; it < N_ITERS; ++it) {
        float vv[16];
#pragma unroll
        for (int p = 0; p < 2; ++p) {
            float4 a = *(const float4*)&vls[(p << 9) + (lane << 3)];
            float4 c = *(const float4*)&vls[(p << 9) + (lane << 3) + 4];
            vv[p * 8 + 0] = a.x; vv[p * 8 + 1] = a.y; vv[p * 8 + 2] = a.z; vv[p * 8 + 3] = a.w;
            vv[p * 8 + 4] = c.x; vv[p * 8 + 5] = c.y; vv[p * 8 + 6] = c.z; vv[p * 8 + 7] = c.w;
        }
        pls[t] = 0.0f;
        if (t < 32) pls[1024 + t] = 0.0f;
        __syncthreads();

        float colacc[16] = {};
#pragma unroll
        for (int rr = 0; rr < 4; ++rr) {
            const int row = (w << 2) + rr;
            float e[16], s = 0.0f;
#pragma unroll
            for (int p = 0; p < 2; ++p) {
                uint4 hx = *(const uint4*)&Eld[row * EPITCH + (p << 9) + (lane << 3)];
                const __half* hp = (const __half*)&hx;
#pragma unroll
                for (int jj = 0; jj < 8; ++jj) {
                    float ev = __half2float(hp[jj]);
                    e[p * 8 + jj] = ev;
                    s += ev * vv[p * 8 + jj];
                }
            }
#pragma unroll
            for (int off = 32; off > 0; off >>= 1) s += __shfl_xor(s, off);
            const float ui = 1.0f / s;
            if (lane == 0) uls[row] = ui;
#pragma unroll
            for (int jj = 0; jj < 16; ++jj) colacc[jj] += e[jj] * ui;
        }
        // swizzled LDS combine: banks spread, 2-way max (free)
#pragma unroll
        for (int p = 0; p < 2; ++p)
#pragma unroll
            for (int jj = 0; jj < 8; ++jj) {
                const int col = (p << 9) + (lane << 3) + jj;
                atomicAdd(&pls[PADIDX(col)], colacc[p * 8 + jj]);
            }
        __syncthreads();

        // global accumulate: ONE device-scope atomicAdd per thread into this
        // iteration's pre-zeroed per-bh slot (LLC-coherent, no fence needed).
        float* pg = part_g + (((it << 4) + bh) << 10);
        atomicAdd(&pg[t], pls[PADIDX(t)]);
        __syncthreads();   // vmcnt(0): all 16 waves' adds performed at LLC

        if (t == 0) {
            __hip_atomic_fetch_add(&cnt[(it << 4) + bh], 1, __ATOMIC_RELEASE,
                                   __HIP_MEMORY_SCOPE_AGENT);
            // RELAXED spin: no cache-maintenance per poll
            while (__hip_atomic_load(&cnt[(it << 4) + bh], __ATOMIC_RELAXED,
                                     __HIP_MEMORY_SCOPE_AGENT) < 16)
                __builtin_amdgcn_s_sleep(1);
            // single acquire to order subsequent reads (one inv per block-iter)
            (void)__hip_atomic_load(&cnt[(it << 4) + bh], __ATOMIC_ACQUIRE,
                                    __HIP_MEMORY_SCOPE_AGENT);
        }
        __syncthreads();

        // merged total: plain coalesced load (slot first-touched after acquire)
        const float sv = pg[t];
        vls[t] = 1.0f / sv;
        __syncthreads();
    }

    // ---- P = u * E * v -> bf16 in place (conflict-free, same mapping as sweep) ----
    {
        float vvf[16];
#pragma unroll
        for (int p = 0; p < 2; ++p) {
            float4 a = *(const float4*)&vls[(p << 9) + (lane << 3)];
            float4 c = *(const float4*)&vls[(p << 9) + (lane << 3) + 4];
            vvf[p * 8 + 0] = a.x; vvf[p * 8 + 1] = a.y; vvf[p * 8 + 2] = a.z; vvf[p * 8 + 3] = a.w;
            vvf[p * 8 + 4] = c.x; vvf[p * 8 + 5] = c.y; vvf[p * 8 + 6] = c.z; vvf[p * 8 + 7] = c.w;
        }
#pragma unroll
        for (int rr = 0; rr < 4; ++rr) {
            const int row = (w << 2) + rr;
            const float ur = uls[row];
#pragma unroll
            for (int p = 0; p < 2; ++p) {
                uint4 hx = *(const uint4*)&Eld[row * EPITCH + (p << 9) + (lane << 3)];
                const __half* hp = (const __half*)&hx;
                unsigned short pk[8];
#pragma unroll
                for (int jj = 0; jj < 8; ++jj)
                    pk[jj] = f2bf(__half2float(hp[jj]) * ur * vvf[p * 8 + jj]);
                *(uint4*)&Eld[row * EPITCH + (p << 9) + (lane << 3)] = *(const uint4*)pk;
            }
        }
    }
    __syncthreads();

    // ---- O(64x64) = P(64x1024) @ V : A from LDS (padded pitch -> even banks), B from vt ----
    {
        const int wr = w >> 2, wc = w & 3;
        const size_t vtb = ((size_t)bh << 16) + ((size_t)((wc << 4) + l16) << 10);
        const int prow = ((wr << 4) + l16) * EPITCH;
        floatx4 oa0 = {}, oa1 = {};
#pragma unroll 4
        for (int ks = 0; ks < 16; ++ks) {
            short8 pa = *(const short8*)&Eld[prow + (ks << 5) + (quad << 3)];
            short8 vb = *(const short8*)&vt[vtb + (ks << 5) + (quad << 3)];
            oa0 = __builtin_amdgcn_mfma_f32_16x16x32_bf16(pa, vb, oa0, 0, 0, 0);
        }
#pragma unroll 4
        for (int ks = 16; ks < 32; ++ks) {
            short8 pa = *(const short8*)&Eld[prow + (ks << 5) + (quad << 3)];
            short8 vb = *(const short8*)&vt[vtb + (ks << 5) + (quad << 3)];
            oa1 = __builtin_amdgcn_mfma_f32_16x16x32_bf16(pa, vb, oa1, 0, 0, 0);
        }
        const int b = bh >> 3, h = bh & 7;
        const int dcol = (wc << 4) + l16;
#pragma unroll
        for (int p = 0; p < 4; ++p) {
            int l = m0 + (wr << 4) + (quad << 2) + p;
            o_p[((size_t)((b << 10) + l) << 9) + (h << 6) + dcol] = f2bf(oa0[p] + oa1[p]);
        }
    }
}

// ---------------- out = out_pre(bf16) @ Wo + bo via MFMA ----------------
__global__ __launch_bounds__(256) void mfma_out(
    const unsigned short* __restrict__ A,   // 2048 x 512 bf16
    const unsigned short* __restrict__ BT,  // woT: 1024 x 512 bf16
    const float* __restrict__ bo, float* __restrict__ C)
{
    __shared__ __align__(16) unsigned short Als[128 * 40];
    __shared__ __align__(16) unsigned short Bls[128 * 40];
    const int t = threadIdx.x;
    const int m0 = blockIdx.y << 7, n0 = blockIdx.x << 7;
    const int w = t >> 6, lane = t & 63;
    const int quad = lane >> 4, l16 = lane & 15;
    const int wr = w >> 1, wc = w & 1;
    const int ra = t >> 2, ka = (t & 3) << 3;
    floatx4 acc[4][4] = {};
    for (int k0 = 0; k0 < N_HD; k0 += 32) {
        uint4 a0 = *(const uint4*)&A[(size_t)(m0 + ra) * N_HD + k0 + ka];
        uint4 a1 = *(const uint4*)&A[(size_t)(m0 + ra + 64) * N_HD + k0 + ka];
        uint4 b0 = *(const uint4*)&BT[(size_t)(n0 + ra) * N_HD + k0 + ka];
        uint4 b1 = *(const uint4*)&BT[(size_t)(n0 + ra + 64) * N_HD + k0 + ka];
        __syncthreads();
        *(uint4*)&Als[ra * 40 + ka] = a0;
        *(uint4*)&Als[(ra + 64) * 40 + ka] = a1;
        *(uint4*)&Bls[ra * 40 + ka] = b0;
        *(uint4*)&Bls[(ra + 64) * 40 + ka] = b1;
        __syncthreads();
        short8 af[4], bf[4];
#pragma unroll
        for (int i = 0; i < 4; ++i)
            af[i] = *(const short8*)&Als[(wr * 64 + i * 16 + l16) * 40 + quad * 8];
#pragma unroll
        for (int j = 0; j < 4; ++j)
            bf[j] = *(const short8*)&Bls[(wc * 64 + j * 16 + l16) * 40 + quad * 8];
#pragma unroll
        for (int i = 0; i < 4; ++i)
#pragma unroll
            for (int j = 0; j < 4; ++j)
                acc[i][j] = __builtin_amdgcn_mfma_f32_16x16x32_bf16(af[i], bf[j], acc[i][j], 0, 0, 0);
    }
    float bje[4];
    int nn[4];
#pragma unroll
    for (int j = 0; j < 4; ++j) {
        nn[j] = n0 + wc * 64 + j * 16 + l16;
        bje[j] = bo[nn[j]];
    }
#pragma unroll
    for (int i = 0; i < 4; ++i)
#pragma unroll
    for (int p = 0; p < 4; ++p) {
        int m = m0 + wr * 64 + i * 16 + quad * 4 + p;
#pragma unroll
        for (int j = 0; j < 4; ++j)
            C[(size_t)m * N_EMB + nn[j]] = acc[i][j][p] + bje[j];
    }
}

extern "C" void kernel_launch(void* const* d_in, const int* in_sizes, int n_in,
                              void* d_out, int out_size, void* d_ws, size_t ws_size,
                              hipStream_t stream)
{
    const float* x  = (const float*)d_in[0];
    const float* Wq = (const float*)d_in[1];
    const float* bq = (const float*)d_in[2];
    const float* Wk = (const float*)d_in[3];
    const float* bk = (const float*)d_in[4];
    const float* Wv = (const float*)d_in[5];
    const float* bv = (const float*)d_in[6];
    const float* Wo = (const float*)d_in[7];
    const float* bo = (const float*)d_in[8];
    float* out = (float*)d_out;

    char* W = (char*)d_ws;
    unsigned short* xb  = (unsigned short*)(W);                    // 4 MB
    unsigned short* wqT = (unsigned short*)(W + (4ll  << 20));     // 1 MB
    unsigned short* wkT = (unsigned short*)(W + (5ll  << 20));     // 1 MB
    unsigned short* wvT = (unsigned short*)(W + (6ll  << 20));     // 1 MB
    unsigned short* woT = (unsigned short*)(W + (7ll  << 20));     // 1 MB
    unsigned short* qb  = (unsigned short*)(W + (8ll  << 20));     // 2 MB
    unsigned short* kb  = (unsigned short*)(W + (10ll << 20));     // 2 MB
    unsigned short* vt  = (unsigned short*)(W + (12ll << 20));     // 2 MB
    unsigned short* o_p = (unsigned short*)(W + (14ll << 20));     // 2 MB
    float* part_g       = (float*)(W + (16ll << 20));              // 1.25 MB (20 slots)
    int* cnt            = (int*)(W + (18ll << 20));                // 1.25 KB

    convert_x<<<512, 256, 0, stream>>>(x, xb);
    transpose_all<<<dim3(32, 32, 4), 256, 0, stream>>>(Wq, Wk, Wv, Wo, wqT, wkT, wvT, woT);
    zero_ws<<<1282, 256, 0, stream>>>(part_g, cnt);
    mfma_qkv<<<dim3(4, 16, 3), 256, 0, stream>>>(xb, wqT, wkT, wvT, bq, bk, bv, qb, kb, vt);

    void* fargs[] = { (void*)&qb, (void*)&kb, (void*)&vt,
                      (void*)&part_g, (void*)&cnt, (void*)&o_p };
    hipLaunchCooperativeKernel((const void*)fused_sinkhorn, dim3(256), dim3(1024),
                               fargs, SMEM_FUSED, stream);

    mfma_out<<<dim3(8, 16), 256, 0, stream>>>(o_p, woT, bo, out);
}

// Round 4
// 695.183 us; speedup vs baseline: 4.7103x; 1.1128x over previous
//
#include <hip/hip_runtime.h>
#include <hip/hip_fp16.h>
#include <math.h>

#define L_SEQ 1024
#define N_EMB 1024
#define N_HD 512
#define N_ITERS 20
#define EPITCH 1032   // 64 rows x 1032 halfs (pad 8) -> row stride 2064B, 16B aligned
// pls index swizzle (+1 float per 32)
#define PADIDX(c) ((c) + ((c) >> 5))
#define SMEM_FUSED (64 * EPITCH * 2 + 4096 + 4224 + 256)

typedef short short8 __attribute__((ext_vector_type(8)));   // 8 bf16 = 4 VGPRs
typedef float floatx4 __attribute__((ext_vector_type(4)));  // MFMA acc

__device__ __forceinline__ unsigned short f2bf(float f) {
    unsigned int u = __float_as_uint(f);
    u += 0x7FFFu + ((u >> 16) & 1u);   // round-to-nearest-even
    return (unsigned short)(u >> 16);
}

// ---------------- prep: fp32 -> bf16 ----------------
__global__ __launch_bounds__(256) void convert_x(const float* __restrict__ x,
                                                 unsigned short* __restrict__ xb) {
    const int i = (blockIdx.x * 256 + threadIdx.x) << 4;  // 16 elems/thread
    unsigned short tmp[16];
#pragma unroll
    for (int p = 0; p < 4; ++p) {
        float4 f = *(const float4*)&x[i + (p << 2)];
        tmp[p * 4 + 0] = f2bf(f.x); tmp[p * 4 + 1] = f2bf(f.y);
        tmp[p * 4 + 2] = f2bf(f.z); tmp[p * 4 + 3] = f2bf(f.w);
    }
    *(uint4*)&xb[i]     = *(const uint4*)&tmp[0];
    *(uint4*)&xb[i + 8] = *(const uint4*)&tmp[8];
}

// Transpose all 4 weights to [n][k] bf16. z: 0..2 = Wq/Wk/Wv (1024x512), 3 = Wo (512x1024)
__global__ __launch_bounds__(256) void transpose_all(
    const float* __restrict__ Wq, const float* __restrict__ Wk,
    const float* __restrict__ Wv, const float* __restrict__ Wo,
    unsigned short* __restrict__ wqT, unsigned short* __restrict__ wkT,
    unsigned short* __restrict__ wvT, unsigned short* __restrict__ woT)
{
    const int z = blockIdx.z;
    const float* S; unsigned short* D; int rows, cols;
    if (z == 0)      { S = Wq; D = wqT; rows = 1024; cols = 512; }
    else if (z == 1) { S = Wk; D = wkT; rows = 1024; cols = 512; }
    else if (z == 2) { S = Wv; D = wvT; rows = 1024; cols = 512; }
    else             { S = Wo; D = woT; rows = 512;  cols = 1024; }
    const int n0 = blockIdx.x << 5, k0 = blockIdx.y << 5;
    if (n0 >= cols || k0 >= rows) return;
    __shared__ float Tls[32][33];
    const int t = threadIdx.x;
    const int rl = t >> 5, cl = t & 31;
#pragma unroll
    for (int i = 0; i < 4; ++i)
        Tls[rl + (i << 3)][cl] = S[(size_t)(k0 + rl + (i << 3)) * cols + n0 + cl];
    __syncthreads();
#pragma unroll
    for (int i = 0; i < 4; ++i)
        D[(size_t)(n0 + rl + (i << 3)) * rows + k0 + cl] = f2bf(Tls[cl][rl + (i << 3)]);
}

// ---------------- zero the barrier counters (part slots are overwrite-only now) ----
__global__ void zero_cnt(int* __restrict__ cnt) {
    if ((int)threadIdx.x < N_ITERS * 16) cnt[threadIdx.x] = 0;
}

// ---------------- bf16 MFMA QKV projection ----------------
// q,k bf16 [bh][l][d]; v bf16 TRANSPOSED [bh][d][l]
__global__ __launch_bounds__(256) void mfma_qkv(
    const unsigned short* __restrict__ xb,
    const unsigned short* __restrict__ wqT, const unsigned short* __restrict__ wkT,
    const unsigned short* __restrict__ wvT,
    const float* __restrict__ bq, const float* __restrict__ bk, const float* __restrict__ bv,
    unsigned short* __restrict__ qb, unsigned short* __restrict__ kb,
    unsigned short* __restrict__ vt)
{
    const int pz = blockIdx.z;
    const unsigned short* wT = (pz == 0) ? wqT : (pz == 1) ? wkT : wvT;
    const float* bias = (pz == 0) ? bq : (pz == 1) ? bk : bv;
    __shared__ __align__(16) unsigned short Als[128 * 40];
    __shared__ __align__(16) unsigned short Bls[128 * 40];
    const int t = threadIdx.x;
    const int m0 = blockIdx.y << 7, n0 = blockIdx.x << 7;
    const int w = t >> 6, lane = t & 63;
    const int quad = lane >> 4, l16 = lane & 15;
    const int wr = w >> 1, wc = w & 1;
    const int ra = t >> 2, ka = (t & 3) << 3;
    floatx4 acc[4][4] = {};
    for (int k0 = 0; k0 < N_EMB; k0 += 32) {
        uint4 a0 = *(const uint4*)&xb[(size_t)(m0 + ra) * N_EMB + k0 + ka];
        uint4 a1 = *(const uint4*)&xb[(size_t)(m0 + ra + 64) * N_EMB + k0 + ka];
        uint4 b0 = *(const uint4*)&wT[(size_t)(n0 + ra) * N_EMB + k0 + ka];
        uint4 b1 = *(const uint4*)&wT[(size_t)(n0 + ra + 64) * N_EMB + k0 + ka];
        __syncthreads();
        *(uint4*)&Als[ra * 40 + ka] = a0;
        *(uint4*)&Als[(ra + 64) * 40 + ka] = a1;
        *(uint4*)&Bls[ra * 40 + ka] = b0;
        *(uint4*)&Bls[(ra + 64) * 40 + ka] = b1;
        __syncthreads();
        short8 af[4], bf[4];
#pragma unroll
        for (int i = 0; i < 4; ++i)
            af[i] = *(const short8*)&Als[(wr * 64 + i * 16 + l16) * 40 + quad * 8];
#pragma unroll
        for (int j = 0; j < 4; ++j)
            bf[j] = *(const short8*)&Bls[(wc * 64 + j * 16 + l16) * 40 + quad * 8];
#pragma unroll
        for (int i = 0; i < 4; ++i)
#pragma unroll
            for (int j = 0; j < 4; ++j)
                acc[i][j] = __builtin_amdgcn_mfma_f32_16x16x32_bf16(af[i], bf[j], acc[i][j], 0, 0, 0);
    }
    float bje[4];
    int hh[4], dd[4];
#pragma unroll
    for (int j = 0; j < 4; ++j) {
        int gn = n0 + wc * 64 + j * 16 + l16;
        bje[j] = bias[gn];
        hh[j] = gn >> 6; dd[j] = gn & 63;
    }
    unsigned short* qk = (pz == 0) ? qb : kb;
#pragma unroll
    for (int i = 0; i < 4; ++i)
#pragma unroll
    for (int p = 0; p < 4; ++p) {
        int gm = m0 + wr * 64 + i * 16 + quad * 4 + p;
        int bb = gm >> 10, l = gm & 1023;
#pragma unroll
        for (int j = 0; j < 4; ++j) {
            float val = acc[i][j][p] + bje[j];
            int bh = (bb << 3) + hh[j];
            if (pz < 2) qk[((size_t)bh * L_SEQ + l) * 64 + dd[j]] = f2bf(val);
            else        vt[((size_t)bh << 16) + ((size_t)dd[j] << 10) + l] = f2bf(val);
        }
    }
}

// ---------------- persistent fused: logits + 20 sinkhorn iters + P@V ----------------
// 256 blocks (bh = bid&15, chunk = bid>>4), 1024 threads, 1 block/CU.
// E tile (64 rows x 1024 cols, fp16, pitch 1032) lives entirely in LDS.
// Exchange: relaxed agent atomic STORES to private per-chunk slots (no RMW
// contention at the coherence point), relaxed counter barrier, relaxed-load merge.
__global__ __launch_bounds__(1024, 4) void fused_sinkhorn(
    const unsigned short* __restrict__ qb, const unsigned short* __restrict__ kb,
    const unsigned short* __restrict__ vt, float* __restrict__ part_g,
    int* __restrict__ cnt, unsigned short* __restrict__ o_p)
{
    extern __shared__ char smem[];
    __half* Eld = (__half*)smem;                                   // 132096 B
    float* vls  = (float*)(smem + 64 * EPITCH * 2);                // 4096 B
    float* pls  = (float*)(smem + 64 * EPITCH * 2 + 4096);         // 4224 B (swizzled 1056)
    float* uls  = (float*)(smem + 64 * EPITCH * 2 + 4096 + 4224);  // 256 B

    const int bid = blockIdx.x;
    const int bh = bid & 15;          // same-bh siblings land on one XCD (perf only)
    const int chunk = bid >> 4;
    const int m0 = chunk << 6;
    const int t = threadIdx.x;
    const int w = t >> 6, lane = t & 63;
    const int quad = lane >> 4, l16 = lane & 15;

    // ---- phase 0: E = exp(Q K^T / 8) -> LDS fp16 ----
    {
        const int wr = w & 3, ns = w >> 2;   // 4 row-subtiles x 4 col-strips of 256
        const size_t qrow = ((size_t)(bh << 10) + m0 + (wr << 4) + l16) * 64;
        short8 af0 = *(const short8*)&qb[qrow + quad * 8];
        short8 af1 = *(const short8*)&qb[qrow + 32 + quad * 8];
        const int erow0 = (wr << 4) + (quad << 2);
        for (int tt = 0; tt < 16; ++tt) {
            const int n0 = (ns << 8) + (tt << 4);
            const size_t krow = ((size_t)(bh << 10) + n0 + l16) * 64;
            short8 bf0 = *(const short8*)&kb[krow + quad * 8];
            short8 bf1 = *(const short8*)&kb[krow + 32 + quad * 8];
            floatx4 acc = {};
            acc = __builtin_amdgcn_mfma_f32_16x16x32_bf16(af0, bf0, acc, 0, 0, 0);
            acc = __builtin_amdgcn_mfma_f32_16x16x32_bf16(af1, bf1, acc, 0, 0, 0);
#pragma unroll
            for (int p = 0; p < 4; ++p)
                Eld[(erow0 + p) * EPITCH + n0 + l16] = __float2half(__expf(acc[p] * 0.125f));
        }
    }
    vls[t] = 1.0f;
    __syncthreads();

    // ---- 20 sinkhorn iterations, E stays in LDS ----
    for (int it = 0; it < N_ITERS; ++it) {
        float vv[16];
#pragma unroll
        for (int p = 0; p < 2; ++p) {
            float4 a = *(const float4*)&vls[(p << 9) + (lane << 3)];
            float4 c = *(const float4*)&vls[(p << 9) + (lane << 3) + 4];
            vv[p * 8 + 0] = a.x; vv[p * 8 + 1] = a.y; vv[p * 8 + 2] = a.z; vv[p * 8 + 3] = a.w;
            vv[p * 8 + 4] = c.x; vv[p * 8 + 5] = c.y; vv[p * 8 + 6] = c.z; vv[p * 8 + 7] = c.w;
        }
        pls[t] = 0.0f;
        if (t < 32) pls[1024 + t] = 0.0f;
        __syncthreads();

        float colacc[16] = {};
#pragma unroll
        for (int rr = 0; rr < 4; ++rr) {
            const int row = (w << 2) + rr;
            float e[16], s = 0.0f;
#pragma unroll
            for (int p = 0; p < 2; ++p) {
                uint4 hx = *(const uint4*)&Eld[row * EPITCH + (p << 9) + (lane << 3)];
                const __half* hp = (const __half*)&hx;
#pragma unroll
                for (int jj = 0; jj < 8; ++jj) {
                    float ev = __half2float(hp[jj]);
                    e[p * 8 + jj] = ev;
                    s += ev * vv[p * 8 + jj];
                }
            }
#pragma unroll
            for (int off = 32; off > 0; off >>= 1) s += __shfl_xor(s, off);
            const float ui = 1.0f / s;
            if (lane == 0) uls[row] = ui;
#pragma unroll
            for (int jj = 0; jj < 16; ++jj) colacc[jj] += e[jj] * ui;
        }
        // LDS combine across the 16 waves (swizzled banks, cheap)
#pragma unroll
        for (int p = 0; p < 2; ++p)
#pragma unroll
            for (int jj = 0; jj < 8; ++jj) {
                const int col = (p << 9) + (lane << 3) + jj;
                atomicAdd(&pls[PADIDX(col)], colacc[p * 8 + jj]);
            }
        __syncthreads();

        // publish: relaxed agent atomic store into this block's private slot
        // (bypasses L2 to the coherence point; pure store stream, zero RMW)
        float* pg = part_g + ((size_t)(((it << 4) + bh) << 4) + chunk) * 1024;
        __hip_atomic_store(&pg[t], pls[PADIDX(t)], __ATOMIC_RELAXED,
                           __HIP_MEMORY_SCOPE_AGENT);
        __syncthreads();   // vmcnt(0) per wave: all 16 waves' stores performed

        if (t == 0) {
            __hip_atomic_fetch_add(&cnt[(it << 4) + bh], 1, __ATOMIC_RELAXED,
                                   __HIP_MEMORY_SCOPE_AGENT);
            while (__hip_atomic_load(&cnt[(it << 4) + bh], __ATOMIC_RELAXED,
                                     __HIP_MEMORY_SCOPE_AGENT) < 16)
                __builtin_amdgcn_s_sleep(1);
        }
        __syncthreads();

        // merge: 16 relaxed agent loads (coalesced 4KB-apart streams), local sum
        const float* pb = part_g + ((size_t)((it << 4) + bh) << 14);
        float sv = 0.0f;
#pragma unroll
        for (int c = 0; c < 16; ++c)
            sv += __hip_atomic_load(&pb[(c << 10) + t], __ATOMIC_RELAXED,
                                    __HIP_MEMORY_SCOPE_AGENT);
        vls[t] = 1.0f / sv;
        __syncthreads();
    }

    // ---- P = u * E * v -> bf16 in place (conflict-free, same mapping as sweep) ----
    {
        float vvf[16];
#pragma unroll
        for (int p = 0; p < 2; ++p) {
            float4 a = *(const float4*)&vls[(p << 9) + (lane << 3)];
            float4 c = *(const float4*)&vls[(p << 9) + (lane << 3) + 4];
            vvf[p * 8 + 0] = a.x; vvf[p * 8 + 1] = a.y; vvf[p * 8 + 2] = a.z; vvf[p * 8 + 3] = a.w;
            vvf[p * 8 + 4] = c.x; vvf[p * 8 + 5] = c.y; vvf[p * 8 + 6] = c.z; vvf[p * 8 + 7] = c.w;
        }
#pragma unroll
        for (int rr = 0; rr < 4; ++rr) {
            const int row = (w << 2) + rr;
            const float ur = uls[row];
#pragma unroll
            for (int p = 0; p < 2; ++p) {
                uint4 hx = *(const uint4*)&Eld[row * EPITCH + (p << 9) + (lane << 3)];
                const __half* hp = (const __half*)&hx;
                unsigned short pk[8];
#pragma unroll
                for (int jj = 0; jj < 8; ++jj)
                    pk[jj] = f2bf(__half2float(hp[jj]) * ur * vvf[p * 8 + jj]);
                *(uint4*)&Eld[row * EPITCH + (p << 9) + (lane << 3)] = *(const uint4*)pk;
            }
        }
    }
    __syncthreads();

    // ---- O(64x64) = P(64x1024) @ V : A from LDS (padded pitch -> even banks), B from vt ----
    {
        const int wr = w >> 2, wc = w & 3;
        const size_t vtb = ((size_t)bh << 16) + ((size_t)((wc << 4) + l16) << 10);
        const int prow = ((wr << 4) + l16) * EPITCH;
        floatx4 oa0 = {}, oa1 = {};
#pragma unroll 4
        for (int ks = 0; ks < 16; ++ks) {
            short8 pa = *(const short8*)&Eld[prow + (ks << 5) + (quad << 3)];
            short8 vb = *(const short8*)&vt[vtb + (ks << 5) + (quad << 3)];
            oa0 = __builtin_amdgcn_mfma_f32_16x16x32_bf16(pa, vb, oa0, 0, 0, 0);
        }
#pragma unroll 4
        for (int ks = 16; ks < 32; ++ks) {
            short8 pa = *(const short8*)&Eld[prow + (ks << 5) + (quad << 3)];
            short8 vb = *(const short8*)&vt[vtb + (ks << 5) + (quad << 3)];
            oa1 = __builtin_amdgcn_mfma_f32_16x16x32_bf16(pa, vb, oa1, 0, 0, 0);
        }
        const int b = bh >> 3, h = bh & 7;
        const int dcol = (wc << 4) + l16;
#pragma unroll
        for (int p = 0; p < 4; ++p) {
            int l = m0 + (wr << 4) + (quad << 2) + p;
            o_p[((size_t)((b << 10) + l) << 9) + (h << 6) + dcol] = f2bf(oa0[p] + oa1[p]);
        }
    }
}

// ---------------- out = out_pre(bf16) @ Wo + bo via MFMA ----------------
__global__ __launch_bounds__(256) void mfma_out(
    const unsigned short* __restrict__ A,   // 2048 x 512 bf16
    const unsigned short* __restrict__ BT,  // woT: 1024 x 512 bf16
    const float* __restrict__ bo, float* __restrict__ C)
{
    __shared__ __align__(16) unsigned short Als[128 * 40];
    __shared__ __align__(16) unsigned short Bls[128 * 40];
    const int t = threadIdx.x;
    const int m0 = blockIdx.y << 7, n0 = blockIdx.x << 7;
    const int w = t >> 6, lane = t & 63;
    const int quad = lane >> 4, l16 = lane & 15;
    const int wr = w >> 1, wc = w & 1;
    const int ra = t >> 2, ka = (t & 3) << 3;
    floatx4 acc[4][4] = {};
    for (int k0 = 0; k0 < N_HD; k0 += 32) {
        uint4 a0 = *(const uint4*)&A[(size_t)(m0 + ra) * N_HD + k0 + ka];
        uint4 a1 = *(const uint4*)&A[(size_t)(m0 + ra + 64) * N_HD + k0 + ka];
        uint4 b0 = *(const uint4*)&BT[(size_t)(n0 + ra) * N_HD + k0 + ka];
        uint4 b1 = *(const uint4*)&BT[(size_t)(n0 + ra + 64) * N_HD + k0 + ka];
        __syncthreads();
        *(uint4*)&Als[ra * 40 + ka] = a0;
        *(uint4*)&Als[(ra + 64) * 40 + ka] = a1;
        *(uint4*)&Bls[ra * 40 + ka] = b0;
        *(uint4*)&Bls[(ra + 64) * 40 + ka] = b1;
        __syncthreads();
        short8 af[4], bf[4];
#pragma unroll
        for (int i = 0; i < 4; ++i)
            af[i] = *(const short8*)&Als[(wr * 64 + i * 16 + l16) * 40 + quad * 8];
#pragma unroll
        for (int j = 0; j < 4; ++j)
            bf[j] = *(const short8*)&Bls[(wc * 64 + j * 16 + l16) * 40 + quad * 8];
#pragma unroll
        for (int i = 0; i < 4; ++i)
#pragma unroll
            for (int j = 0; j < 4; ++j)
                acc[i][j] = __builtin_amdgcn_mfma_f32_16x16x32_bf16(af[i], bf[j], acc[i][j], 0, 0, 0);
    }
    float bje[4];
    int nn[4];
#pragma unroll
    for (int j = 0; j < 4; ++j) {
        nn[j] = n0 + wc * 64 + j * 16 + l16;
        bje[j] = bo[nn[j]];
    }
#pragma unroll
    for (int i = 0; i < 4; ++i)
#pragma unroll
    for (int p = 0; p < 4; ++p) {
        int m = m0 + wr * 64 + i * 16 + quad * 4 + p;
#pragma unroll
        for (int j = 0; j < 4; ++j)
            C[(size_t)m * N_EMB + nn[j]] = acc[i][j][p] + bje[j];
    }
}

extern "C" void kernel_launch(void* const* d_in, const int* in_sizes, int n_in,
                              void* d_out, int out_size, void* d_ws, size_t ws_size,
                              hipStream_t stream)
{
    const float* x  = (const float*)d_in[0];
    const float* Wq = (const float*)d_in[1];
    const float* bq = (const float*)d_in[2];
    const float* Wk = (const float*)d_in[3];
    const float* bk = (const float*)d_in[4];
    const float* Wv = (const float*)d_in[5];
    const float* bv = (const float*)d_in[6];
    const float* Wo = (const float*)d_in[7];
    const float* bo = (const float*)d_in[8];
    float* out = (float*)d_out;

    char* W = (char*)d_ws;
    unsigned short* xb  = (unsigned short*)(W);                    // 4 MB
    unsigned short* wqT = (unsigned short*)(W + (4ll  << 20));     // 1 MB
    unsigned short* wkT = (unsigned short*)(W + (5ll  << 20));     // 1 MB
    unsigned short* wvT = (unsigned short*)(W + (6ll  << 20));     // 1 MB
    unsigned short* woT = (unsigned short*)(W + (7ll  << 20));     // 1 MB
    unsigned short* qb  = (unsigned short*)(W + (8ll  << 20));     // 2 MB
    unsigned short* kb  = (unsigned short*)(W + (10ll << 20));     // 2 MB
    unsigned short* vt  = (unsigned short*)(W + (12ll << 20));     // 2 MB
    unsigned short* o_p = (unsigned short*)(W + (14ll << 20));     // 2 MB
    float* part_g       = (float*)(W + (16ll << 20));              // 20 MB (per-chunk slots)
    int* cnt            = (int*)(W + (37ll << 20));                // 1.25 KB

    convert_x<<<512, 256, 0, stream>>>(x, xb);
    transpose_all<<<dim3(32, 32, 4), 256, 0, stream>>>(Wq, Wk, Wv, Wo, wqT, wkT, wvT, woT);
    zero_cnt<<<1, 320, 0, stream>>>(cnt);
    mfma_qkv<<<dim3(4, 16, 3), 256, 0, stream>>>(xb, wqT, wkT, wvT, bq, bk, bv, qb, kb, vt);

    void* fargs[] = { (void*)&qb, (void*)&kb, (void*)&vt,
                      (void*)&part_g, (void*)&cnt, (void*)&o_p };
    hipLaunchCooperativeKernel((const void*)fused_sinkhorn, dim3(256), dim3(1024),
                               fargs, SMEM_FUSED, stream);

    mfma_out<<<dim3(8, 16), 256, 0, stream>>>(o_p, woT, bo, out);
}

// Round 5
// 676.552 us; speedup vs baseline: 4.8400x; 1.0275x over previous
//
#include <hip/hip_runtime.h>
#include <hip/hip_fp16.h>
#include <math.h>

#define L_SEQ 1024
#define N_EMB 1024
#define N_HD 512
#define N_ITERS 20
#define EPITCH 1032   // 64 rows x 1032 halfs (pad 8) -> row stride 2064B, 16B aligned
// pls index swizzle (+1 float per 32)
#define PADIDX(c) ((c) + ((c) >> 5))
#define SMEM_FUSED (64 * EPITCH * 2 + 4096 + 4224 + 256)
// each (it,bh) barrier counter gets its own 256B line: stride 64 ints
#define CNT_STRIDE 64
#define CNT_TOTAL (N_ITERS * 16 * CNT_STRIDE)

typedef short short8 __attribute__((ext_vector_type(8)));   // 8 bf16 = 4 VGPRs
typedef float floatx4 __attribute__((ext_vector_type(4)));  // MFMA acc

__device__ __forceinline__ unsigned short f2bf(float f) {
    unsigned int u = __float_as_uint(f);
    u += 0x7FFFu + ((u >> 16) & 1u);   // round-to-nearest-even
    return (unsigned short)(u >> 16);
}

// ---------------- prep: fp32 -> bf16 ----------------
__global__ __launch_bounds__(256) void convert_x(const float* __restrict__ x,
                                                 unsigned short* __restrict__ xb) {
    const int i = (blockIdx.x * 256 + threadIdx.x) << 4;  // 16 elems/thread
    unsigned short tmp[16];
#pragma unroll
    for (int p = 0; p < 4; ++p) {
        float4 f = *(const float4*)&x[i + (p << 2)];
        tmp[p * 4 + 0] = f2bf(f.x); tmp[p * 4 + 1] = f2bf(f.y);
        tmp[p * 4 + 2] = f2bf(f.z); tmp[p * 4 + 3] = f2bf(f.w);
    }
    *(uint4*)&xb[i]     = *(const uint4*)&tmp[0];
    *(uint4*)&xb[i + 8] = *(const uint4*)&tmp[8];
}

// Transpose all 4 weights to [n][k] bf16. z: 0..2 = Wq/Wk/Wv (1024x512), 3 = Wo (512x1024)
__global__ __launch_bounds__(256) void transpose_all(
    const float* __restrict__ Wq, const float* __restrict__ Wk,
    const float* __restrict__ Wv, const float* __restrict__ Wo,
    unsigned short* __restrict__ wqT, unsigned short* __restrict__ wkT,
    unsigned short* __restrict__ wvT, unsigned short* __restrict__ woT)
{
    const int z = blockIdx.z;
    const float* S; unsigned short* D; int rows, cols;
    if (z == 0)      { S = Wq; D = wqT; rows = 1024; cols = 512; }
    else if (z == 1) { S = Wk; D = wkT; rows = 1024; cols = 512; }
    else if (z == 2) { S = Wv; D = wvT; rows = 1024; cols = 512; }
    else             { S = Wo; D = woT; rows = 512;  cols = 1024; }
    const int n0 = blockIdx.x << 5, k0 = blockIdx.y << 5;
    if (n0 >= cols || k0 >= rows) return;
    __shared__ float Tls[32][33];
    const int t = threadIdx.x;
    const int rl = t >> 5, cl = t & 31;
#pragma unroll
    for (int i = 0; i < 4; ++i)
        Tls[rl + (i << 3)][cl] = S[(size_t)(k0 + rl + (i << 3)) * cols + n0 + cl];
    __syncthreads();
#pragma unroll
    for (int i = 0; i < 4; ++i)
        D[(size_t)(n0 + rl + (i << 3)) * rows + k0 + cl] = f2bf(Tls[cl][rl + (i << 3)]);
}

// ---------------- zero the (padded) barrier counters ----------------
__global__ __launch_bounds__(256) void zero_cnt(int* __restrict__ cnt) {
    const int i = blockIdx.x * 256 + threadIdx.x;
    if (i < CNT_TOTAL) cnt[i] = 0;
}

// ---------------- bf16 MFMA QKV projection ----------------
// q,k bf16 [bh][l][d]; v bf16 TRANSPOSED [bh][d][l]
__global__ __launch_bounds__(256) void mfma_qkv(
    const unsigned short* __restrict__ xb,
    const unsigned short* __restrict__ wqT, const unsigned short* __restrict__ wkT,
    const unsigned short* __restrict__ wvT,
    const float* __restrict__ bq, const float* __restrict__ bk, const float* __restrict__ bv,
    unsigned short* __restrict__ qb, unsigned short* __restrict__ kb,
    unsigned short* __restrict__ vt)
{
    const int pz = blockIdx.z;
    const unsigned short* wT = (pz == 0) ? wqT : (pz == 1) ? wkT : wvT;
    const float* bias = (pz == 0) ? bq : (pz == 1) ? bk : bv;
    __shared__ __align__(16) unsigned short Als[128 * 40];
    __shared__ __align__(16) unsigned short Bls[128 * 40];
    const int t = threadIdx.x;
    const int m0 = blockIdx.y << 7, n0 = blockIdx.x << 7;
    const int w = t >> 6, lane = t & 63;
    const int quad = lane >> 4, l16 = lane & 15;
    const int wr = w >> 1, wc = w & 1;
    const int ra = t >> 2, ka = (t & 3) << 3;
    floatx4 acc[4][4] = {};
    for (int k0 = 0; k0 < N_EMB; k0 += 32) {
        uint4 a0 = *(const uint4*)&xb[(size_t)(m0 + ra) * N_EMB + k0 + ka];
        uint4 a1 = *(const uint4*)&xb[(size_t)(m0 + ra + 64) * N_EMB + k0 + ka];
        uint4 b0 = *(const uint4*)&wT[(size_t)(n0 + ra) * N_EMB + k0 + ka];
        uint4 b1 = *(const uint4*)&wT[(size_t)(n0 + ra + 64) * N_EMB + k0 + ka];
        __syncthreads();
        *(uint4*)&Als[ra * 40 + ka] = a0;
        *(uint4*)&Als[(ra + 64) * 40 + ka] = a1;
        *(uint4*)&Bls[ra * 40 + ka] = b0;
        *(uint4*)&Bls[(ra + 64) * 40 + ka] = b1;
        __syncthreads();
        short8 af[4], bf[4];
#pragma unroll
        for (int i = 0; i < 4; ++i)
            af[i] = *(const short8*)&Als[(wr * 64 + i * 16 + l16) * 40 + quad * 8];
#pragma unroll
        for (int j = 0; j < 4; ++j)
            bf[j] = *(const short8*)&Bls[(wc * 64 + j * 16 + l16) * 40 + quad * 8];
#pragma unroll
        for (int i = 0; i < 4; ++i)
#pragma unroll
            for (int j = 0; j < 4; ++j)
                acc[i][j] = __builtin_amdgcn_mfma_f32_16x16x32_bf16(af[i], bf[j], acc[i][j], 0, 0, 0);
    }
    float bje[4];
    int hh[4], dd[4];
#pragma unroll
    for (int j = 0; j < 4; ++j) {
        int gn = n0 + wc * 64 + j * 16 + l16;
        bje[j] = bias[gn];
        hh[j] = gn >> 6; dd[j] = gn & 63;
    }
    unsigned short* qk = (pz == 0) ? qb : kb;
#pragma unroll
    for (int i = 0; i < 4; ++i)
#pragma unroll
    for (int p = 0; p < 4; ++p) {
        int gm = m0 + wr * 64 + i * 16 + quad * 4 + p;
        int bb = gm >> 10, l = gm & 1023;
#pragma unroll
        for (int j = 0; j < 4; ++j) {
            float val = acc[i][j][p] + bje[j];
            int bh = (bb << 3) + hh[j];
            if (pz < 2) qk[((size_t)bh * L_SEQ + l) * 64 + dd[j]] = f2bf(val);
            else        vt[((size_t)bh << 16) + ((size_t)dd[j] << 10) + l] = f2bf(val);
        }
    }
}

// ---------------- persistent fused: logits + 20 sinkhorn iters + P@V ----------------
// 256 blocks (bh = bid&15, chunk = bid>>4), 1024 threads, 1 block/CU.
// E tile (64 rows x 1024 cols, fp16, pitch 1032) lives entirely in LDS.
// Exchange: relaxed agent atomic stores to private slots; arrival counters are
// PADDED TO ONE CACHE LINE EACH (the shared-line fetch_add serialization was
// ~25us/iter across ALL 256 blocks in rounds 2-4).
__global__ __launch_bounds__(1024, 4) void fused_sinkhorn(
    const unsigned short* __restrict__ qb, const unsigned short* __restrict__ kb,
    const unsigned short* __restrict__ vt, float* __restrict__ part_g,
    int* __restrict__ cnt, unsigned short* __restrict__ o_p)
{
    extern __shared__ char smem[];
    __half* Eld = (__half*)smem;                                   // 132096 B
    float* vls  = (float*)(smem + 64 * EPITCH * 2);                // 4096 B
    float* pls  = (float*)(smem + 64 * EPITCH * 2 + 4096);         // 4224 B (swizzled 1056)
    float* uls  = (float*)(smem + 64 * EPITCH * 2 + 4096 + 4224);  // 256 B

    const int bid = blockIdx.x;
    const int bh = bid & 15;          // same-bh siblings land on one XCD (perf only)
    const int chunk = bid >> 4;
    const int m0 = chunk << 6;
    const int t = threadIdx.x;
    const int w = t >> 6, lane = t & 63;
    const int quad = lane >> 4, l16 = lane & 15;

    // ---- phase 0: E = exp(Q K^T / 8) -> LDS fp16 ----
    {
        const int wr = w & 3, ns = w >> 2;   // 4 row-subtiles x 4 col-strips of 256
        const size_t qrow = ((size_t)(bh << 10) + m0 + (wr << 4) + l16) * 64;
        short8 af0 = *(const short8*)&qb[qrow + quad * 8];
        short8 af1 = *(const short8*)&qb[qrow + 32 + quad * 8];
        const int erow0 = (wr << 4) + (quad << 2);
        for (int tt = 0; tt < 16; ++tt) {
            const int n0 = (ns << 8) + (tt << 4);
            const size_t krow = ((size_t)(bh << 10) + n0 + l16) * 64;
            short8 bf0 = *(const short8*)&kb[krow + quad * 8];
            short8 bf1 = *(const short8*)&kb[krow + 32 + quad * 8];
            floatx4 acc = {};
            acc = __builtin_amdgcn_mfma_f32_16x16x32_bf16(af0, bf0, acc, 0, 0, 0);
            acc = __builtin_amdgcn_mfma_f32_16x16x32_bf16(af1, bf1, acc, 0, 0, 0);
#pragma unroll
            for (int p = 0; p < 4; ++p)
                Eld[(erow0 + p) * EPITCH + n0 + l16] = __float2half(__expf(acc[p] * 0.125f));
        }
    }
    vls[t] = 1.0f;
    __syncthreads();

    // ---- 20 sinkhorn iterations, E stays in LDS ----
    for (int it = 0; it < N_ITERS; ++it) {
        float vv[16];
#pragma unroll
        for (int p = 0; p < 2; ++p) {
            float4 a = *(const float4*)&vls[(p << 9) + (lane << 3)];
            float4 c = *(const float4*)&vls[(p << 9) + (lane << 3) + 4];
            vv[p * 8 + 0] = a.x; vv[p * 8 + 1] = a.y; vv[p * 8 + 2] = a.z; vv[p * 8 + 3] = a.w;
            vv[p * 8 + 4] = c.x; vv[p * 8 + 5] = c.y; vv[p * 8 + 6] = c.z; vv[p * 8 + 7] = c.w;
        }
        pls[t] = 0.0f;
        if (t < 32) pls[1024 + t] = 0.0f;
        __syncthreads();

        float colacc[16] = {};
#pragma unroll
        for (int rr = 0; rr < 4; ++rr) {
            const int row = (w << 2) + rr;
            float e[16], s = 0.0f;
#pragma unroll
            for (int p = 0; p < 2; ++p) {
                uint4 hx = *(const uint4*)&Eld[row * EPITCH + (p << 9) + (lane << 3)];
                const __half* hp = (const __half*)&hx;
#pragma unroll
                for (int jj = 0; jj < 8; ++jj) {
                    float ev = __half2float(hp[jj]);
                    e[p * 8 + jj] = ev;
                    s += ev * vv[p * 8 + jj];
                }
            }
#pragma unroll
            for (int off = 32; off > 0; off >>= 1) s += __shfl_xor(s, off);
            const float ui = 1.0f / s;
            if (lane == 0) uls[row] = ui;
#pragma unroll
            for (int jj = 0; jj < 16; ++jj) colacc[jj] += e[jj] * ui;
        }
        // LDS combine across the 16 waves (swizzled banks, cheap)
#pragma unroll
        for (int p = 0; p < 2; ++p)
#pragma unroll
            for (int jj = 0; jj < 8; ++jj) {
                const int col = (p << 9) + (lane << 3) + jj;
                atomicAdd(&pls[PADIDX(col)], colacc[p * 8 + jj]);
            }
        __syncthreads();

        // publish: relaxed agent atomic store into this block's private slot
        float* pg = part_g + ((size_t)(((it << 4) + bh) << 4) + chunk) * 1024;
        __hip_atomic_store(&pg[t], pls[PADIDX(t)], __ATOMIC_RELAXED,
                           __HIP_MEMORY_SCOPE_AGENT);
        __syncthreads();   // vmcnt(0) per wave: all 16 waves' stores performed

        // arrival counter: one 256B line per (it,bh) -> only 16 RMWs serialize
        // on any line, and the 16 bh-groups proceed on independent lines.
        int* cl = &cnt[((it << 4) + bh) * CNT_STRIDE];
        if (t == 0) {
            __hip_atomic_fetch_add(cl, 1, __ATOMIC_RELAXED,
                                   __HIP_MEMORY_SCOPE_AGENT);
            while (__hip_atomic_load(cl, __ATOMIC_RELAXED,
                                     __HIP_MEMORY_SCOPE_AGENT) < 16)
                __builtin_amdgcn_s_sleep(1);
        }
        __syncthreads();

        // merge: 16 relaxed agent loads (coalesced 4KB-apart streams), local sum
        const float* pb = part_g + ((size_t)((it << 4) + bh) << 14);
        float sv = 0.0f;
#pragma unroll
        for (int c = 0; c < 16; ++c)
            sv += __hip_atomic_load(&pb[(c << 10) + t], __ATOMIC_RELAXED,
                                    __HIP_MEMORY_SCOPE_AGENT);
        vls[t] = 1.0f / sv;
        __syncthreads();
    }

    // ---- P = u * E * v -> bf16 in place (conflict-free, same mapping as sweep) ----
    {
        float vvf[16];
#pragma unroll
        for (int p = 0; p < 2; ++p) {
            float4 a = *(const float4*)&vls[(p << 9) + (lane << 3)];
            float4 c = *(const float4*)&vls[(p << 9) + (lane << 3) + 4];
            vvf[p * 8 + 0] = a.x; vvf[p * 8 + 1] = a.y; vvf[p * 8 + 2] = a.z; vvf[p * 8 + 3] = a.w;
            vvf[p * 8 + 4] = c.x; vvf[p * 8 + 5] = c.y; vvf[p * 8 + 6] = c.z; vvf[p * 8 + 7] = c.w;
        }
#pragma unroll
        for (int rr = 0; rr < 4; ++rr) {
            const int row = (w << 2) + rr;
            const float ur = uls[row];
#pragma unroll
            for (int p = 0; p < 2; ++p) {
                uint4 hx = *(const uint4*)&Eld[row * EPITCH + (p << 9) + (lane << 3)];
                const __half* hp = (const __half*)&hx;
                unsigned short pk[8];
#pragma unroll
                for (int jj = 0; jj < 8; ++jj)
                    pk[jj] = f2bf(__half2float(hp[jj]) * ur * vvf[p * 8 + jj]);
                *(uint4*)&Eld[row * EPITCH + (p << 9) + (lane << 3)] = *(const uint4*)pk;
            }
        }
    }
    __syncthreads();

    // ---- O(64x64) = P(64x1024) @ V : A from LDS (padded pitch -> even banks), B from vt ----
    {
        const int wr = w >> 2, wc = w & 3;
        const size_t vtb = ((size_t)bh << 16) + ((size_t)((wc << 4) + l16) << 10);
        const int prow = ((wr << 4) + l16) * EPITCH;
        floatx4 oa0 = {}, oa1 = {};
#pragma unroll 4
        for (int ks = 0; ks < 16; ++ks) {
            short8 pa = *(const short8*)&Eld[prow + (ks << 5) + (quad << 3)];
            short8 vb = *(const short8*)&vt[vtb + (ks << 5) + (quad << 3)];
            oa0 = __builtin_amdgcn_mfma_f32_16x16x32_bf16(pa, vb, oa0, 0, 0, 0);
        }
#pragma unroll 4
        for (int ks = 16; ks < 32; ++ks) {
            short8 pa = *(const short8*)&Eld[prow + (ks << 5) + (quad << 3)];
            short8 vb = *(const short8*)&vt[vtb + (ks << 5) + (quad << 3)];
            oa1 = __builtin_amdgcn_mfma_f32_16x16x32_bf16(pa, vb, oa1, 0, 0, 0);
        }
        const int b = bh >> 3, h = bh & 7;
        const int dcol = (wc << 4) + l16;
#pragma unroll
        for (int p = 0; p < 4; ++p) {
            int l = m0 + (wr << 4) + (quad << 2) + p;
            o_p[((size_t)((b << 10) + l) << 9) + (h << 6) + dcol] = f2bf(oa0[p] + oa1[p]);
        }
    }
}

// ---------------- out = out_pre(bf16) @ Wo + bo via MFMA ----------------
__global__ __launch_bounds__(256) void mfma_out(
    const unsigned short* __restrict__ A,   // 2048 x 512 bf16
    const unsigned short* __restrict__ BT,  // woT: 1024 x 512 bf16
    const float* __restrict__ bo, float* __restrict__ C)
{
    __shared__ __align__(16) unsigned short Als[128 * 40];
    __shared__ __align__(16) unsigned short Bls[128 * 40];
    const int t = threadIdx.x;
    const int m0 = blockIdx.y << 7, n0 = blockIdx.x << 7;
    const int w = t >> 6, lane = t & 63;
    const int quad = lane >> 4, l16 = lane & 15;
    const int wr = w >> 1, wc = w & 1;
    const int ra = t >> 2, ka = (t & 3) << 3;
    floatx4 acc[4][4] = {};
    for (int k0 = 0; k0 < N_HD; k0 += 32) {
        uint4 a0 = *(const uint4*)&A[(size_t)(m0 + ra) * N_HD + k0 + ka];
        uint4 a1 = *(const uint4*)&A[(size_t)(m0 + ra + 64) * N_HD + k0 + ka];
        uint4 b0 = *(const uint4*)&BT[(size_t)(n0 + ra) * N_HD + k0 + ka];
        uint4 b1 = *(const uint4*)&BT[(size_t)(n0 + ra + 64) * N_HD + k0 + ka];
        __syncthreads();
        *(uint4*)&Als[ra * 40 + ka] = a0;
        *(uint4*)&Als[(ra + 64) * 40 + ka] = a1;
        *(uint4*)&Bls[ra * 40 + ka] = b0;
        *(uint4*)&Bls[(ra + 64) * 40 + ka] = b1;
        __syncthreads();
        short8 af[4], bf[4];
#pragma unroll
        for (int i = 0; i < 4; ++i)
            af[i] = *(const short8*)&Als[(wr * 64 + i * 16 + l16) * 40 + quad * 8];
#pragma unroll
        for (int j = 0; j < 4; ++j)
            bf[j] = *(const short8*)&Bls[(wc * 64 + j * 16 + l16) * 40 + quad * 8];
#pragma unroll
        for (int i = 0; i < 4; ++i)
#pragma unroll
            for (int j = 0; j < 4; ++j)
                acc[i][j] = __builtin_amdgcn_mfma_f32_16x16x32_bf16(af[i], bf[j], acc[i][j], 0, 0, 0);
    }
    float bje[4];
    int nn[4];
#pragma unroll
    for (int j = 0; j < 4; ++j) {
        nn[j] = n0 + wc * 64 + j * 16 + l16;
        bje[j] = bo[nn[j]];
    }
#pragma unroll
    for (int i = 0; i < 4; ++i)
#pragma unroll
    for (int p = 0; p < 4; ++p) {
        int m = m0 + wr * 64 + i * 16 + quad * 4 + p;
#pragma unroll
        for (int j = 0; j < 4; ++j)
            C[(size_t)m * N_EMB + nn[j]] = acc[i][j][p] + bje[j];
    }
}

extern "C" void kernel_launch(void* const* d_in, const int* in_sizes, int n_in,
                              void* d_out, int out_size, void* d_ws, size_t ws_size,
                              hipStream_t stream)
{
    const float* x  = (const float*)d_in[0];
    const float* Wq = (const float*)d_in[1];
    const float* bq = (const float*)d_in[2];
    const float* Wk = (const float*)d_in[3];
    const float* bk = (const float*)d_in[4];
    const float* Wv = (const float*)d_in[5];
    const float* bv = (const float*)d_in[6];
    const float* Wo = (const float*)d_in[7];
    const float* bo = (const float*)d_in[8];
    float* out = (float*)d_out;

    char* W = (char*)d_ws;
    unsigned short* xb  = (unsigned short*)(W);                    // 4 MB
    unsigned short* wqT = (unsigned short*)(W + (4ll  << 20));     // 1 MB
    unsigned short* wkT = (unsigned short*)(W + (5ll  << 20));     // 1 MB
    unsigned short* wvT = (unsigned short*)(W + (6ll  << 20));     // 1 MB
    unsigned short* woT = (unsigned short*)(W + (7ll  << 20));     // 1 MB
    unsigned short* qb  = (unsigned short*)(W + (8ll  << 20));     // 2 MB
    unsigned short* kb  = (unsigned short*)(W + (10ll << 20));     // 2 MB
    unsigned short* vt  = (unsigned short*)(W + (12ll << 20));     // 2 MB
    unsigned short* o_p = (unsigned short*)(W + (14ll << 20));     // 2 MB
    float* part_g       = (float*)(W + (16ll << 20));              // 20 MB (per-chunk slots)
    int* cnt            = (int*)(W + (37ll << 20));                // 80 KB (padded lines)

    convert_x<<<512, 256, 0, stream>>>(x, xb);
    transpose_all<<<dim3(32, 32, 4), 256, 0, stream>>>(Wq, Wk, Wv, Wo, wqT, wkT, wvT, woT);
    zero_cnt<<<(CNT_TOTAL + 255) / 256, 256, 0, stream>>>(cnt);
    mfma_qkv<<<dim3(4, 16, 3), 256, 0, stream>>>(xb, wqT, wkT, wvT, bq, bk, bv, qb, kb, vt);

    void* fargs[] = { (void*)&qb, (void*)&kb, (void*)&vt,
                      (void*)&part_g, (void*)&cnt, (void*)&o_p };
    hipLaunchCooperativeKernel((const void*)fused_sinkhorn, dim3(256), dim3(1024),
                               fargs, SMEM_FUSED, stream);

    mfma_out<<<dim3(8, 16), 256, 0, stream>>>(o_p, woT, bo, out);
}